// Round 2
// baseline (697.209 us; speedup 1.0000x reference)
//
#include <hip/hip_runtime.h>
#include <hip/hip_bf16.h>
#include <math.h>

typedef __hip_bfloat16 bf16;
typedef unsigned short u16;
typedef unsigned int u32;

#define LL 36864  // L*L

__device__ __forceinline__ float wave_sum(float v) {
#pragma unroll
  for (int m = 32; m; m >>= 1) v += __shfl_xor(v, m, 64);
  return v;
}
__device__ __forceinline__ float wave_max(float v) {
#pragma unroll
  for (int m = 32; m; m >>= 1) v = fmaxf(v, __shfl_xor(v, m, 64));
  return v;
}

__device__ __forceinline__ float bf2f(u16 u) {
  union { float f; u32 u; } c; c.u = ((u32)u) << 16; return c.f;
}
__device__ __forceinline__ u16 f2bf(float f) {  // RNE, finite values
  union { float f; u32 u; } c; c.f = f;
  u32 r = c.u + 0x7fffu + ((c.u >> 16) & 1u);
  return (u16)(r >> 16);
}
// load 8 consecutive bf16 (16B-aligned) -> f32
__device__ __forceinline__ void ld8(const bf16* p, float* f) {
  uint4 v = *reinterpret_cast<const uint4*>(p);
  const u16* s = reinterpret_cast<const u16*>(&v);
#pragma unroll
  for (int i = 0; i < 8; ++i) f[i] = bf2f(s[i]);
}
// store 4 consecutive bf16 (8B-aligned)
__device__ __forceinline__ void st4(bf16* p, float a, float b, float c, float d) {
  uint2 v;
  v.x = (u32)f2bf(a) | ((u32)f2bf(b) << 16);
  v.y = (u32)f2bf(c) | ((u32)f2bf(d) << 16);
  *reinterpret_cast<uint2*>(p) = v;
}

// ---------------- kernel 1: LayerNorm f32 -> bf16 ----------------
__global__ __launch_bounds__(256) void k_ln(const float* __restrict__ zin,
                                            const float* __restrict__ w,
                                            const float* __restrict__ b,
                                            bf16* __restrict__ zb) {
  int t = threadIdx.x;
  int wv = t >> 6, lane = t & 63;
  size_t m = (size_t)blockIdx.x * 4 + wv;
  const float2 v = *reinterpret_cast<const float2*>(&zin[m * 128 + lane * 2]);
  float s = wave_sum(v.x + v.y);
  float ss = wave_sum(v.x * v.x + v.y * v.y);
  float mean = s * (1.0f / 128.0f);
  float var = ss * (1.0f / 128.0f) - mean * mean;
  float rs = rsqrtf(var + 1e-5f);
  float o0 = (v.x - mean) * rs * w[lane * 2] + b[lane * 2];
  float o1 = (v.y - mean) * rs * w[lane * 2 + 1] + b[lane * 2 + 1];
  u32 pk = (u32)f2bf(o0) | ((u32)f2bf(o1) << 16);
  *reinterpret_cast<u32*>(&zb[m * 128 + lane * 2]) = pk;
}

// ---------------- kernel 1b: bias projection ----------------
// bias_t[h][l][kk] = (z[m]@Wb)[h] + bb[h],  m = kk*192 + l
__global__ __launch_bounds__(256) void k_biasproj(const bf16* __restrict__ zb,
                                                  const float* __restrict__ Wb,
                                                  const float* __restrict__ bbv,
                                                  float* __restrict__ bias_t) {
  int t = threadIdx.x;
  int wv = t >> 6, lane = t & 63;
  int m = blockIdx.x * 4 + wv;
  u32 pk = *reinterpret_cast<const u32*>(&zb[(size_t)m * 128 + lane * 2]);
  float z0 = bf2f((u16)(pk & 0xffff)), z1 = bf2f((u16)(pk >> 16));
  float acc[12];
#pragma unroll
  for (int h = 0; h < 12; ++h)
    acc[h] = z0 * Wb[(lane * 2) * 12 + h] + z1 * Wb[(lane * 2 + 1) * 12 + h];
#pragma unroll
  for (int h = 0; h < 12; ++h) acc[h] = wave_sum(acc[h]);
  if (lane == 0) {
    int kk = m / 192, l = m % 192;
#pragma unroll
    for (int h = 0; h < 12; ++h)
      bias_t[(size_t)h * LL + (size_t)l * 192 + kk] = acc[h] + bbv[h];
  }
}

// ---------------- kernel 2: q,k,v,g projections ----------------
__global__ __launch_bounds__(256) void k_proj(const bf16* __restrict__ zb,
    const float* __restrict__ Wq, const float* __restrict__ bq,
    const float* __restrict__ Wk, const float* __restrict__ bk,
    const float* __restrict__ Wv, const float* __restrict__ bv,
    const float* __restrict__ Wg, const float* __restrict__ bg,
    bf16* __restrict__ qkb, bf16* __restrict__ vb, bf16* __restrict__ gb) {
  __shared__ float As[64 * 68];  // [k][m] transposed
  __shared__ float Bs[64 * 68];  // [k][n]
  int t = threadIdx.x;
  int m0 = blockIdx.x * 64;
  int n0 = blockIdx.y * 64;
  int tx = t & 15, ty = t >> 4;
  int n_l = t & 63;
  int jg_l = n0 + n_l;
  int sec_l = jg_l / 288, j_l = jg_l % 288;
  const float* Wp = (sec_l == 0) ? Wq : (sec_l == 1) ? Wk : (sec_l == 2) ? Wv : Wg;
  float acc[4][4] = {};
  for (int kc = 0; kc < 2; ++kc) {
    __syncthreads();
#pragma unroll
    for (int ii = 0; ii < 2; ++ii) {
      int u = t + ii * 256;           // u in [0,512)
      int r = u >> 3, c = (u & 7) * 8;
      float f[8];
      ld8(&zb[(size_t)(m0 + r) * 128 + kc * 64 + c], f);
#pragma unroll
      for (int i = 0; i < 8; ++i) As[(c + i) * 68 + r] = f[i];
    }
#pragma unroll
    for (int kr = t >> 6; kr < 64; kr += 4)
      Bs[kr * 68 + n_l] = Wp[(size_t)(kc * 64 + kr) * 288 + j_l];
    __syncthreads();
#pragma unroll 8
    for (int k = 0; k < 64; ++k) {
      float4 a = *reinterpret_cast<const float4*>(&As[k * 68 + ty * 4]);
      float4 b4 = *reinterpret_cast<const float4*>(&Bs[k * 68 + tx * 4]);
      float av[4] = {a.x, a.y, a.z, a.w};
      float bvv[4] = {b4.x, b4.y, b4.z, b4.w};
#pragma unroll
      for (int i = 0; i < 4; ++i)
#pragma unroll
        for (int j = 0; j < 4; ++j) acc[i][j] += av[i] * bvv[j];
    }
  }
#pragma unroll
  for (int i = 0; i < 4; ++i) {
    int m = m0 + ty * 4 + i;
    int jg = n0 + tx * 4;
    int sec = jg / 288, jj = jg % 288;
    if (sec == 0) {
      st4(&qkb[(size_t)m * 576 + jj],
          acc[i][0] + bq[jj], acc[i][1] + bq[jj + 1],
          acc[i][2] + bq[jj + 2], acc[i][3] + bq[jj + 3]);
    } else if (sec == 1) {
      st4(&qkb[(size_t)m * 576 + 288 + jj],
          acc[i][0] + bk[jj], acc[i][1] + bk[jj + 1],
          acc[i][2] + bk[jj + 2], acc[i][3] + bk[jj + 3]);
    } else if (sec == 2) {
      int l = m % 192, kk = m / 192;
      int hh = jj / 24, cc = jj % 24;
      st4(&vb[(((size_t)l * 12 + hh) * 192 + kk) * 24 + cc],
          acc[i][0] + bv[jj], acc[i][1] + bv[jj + 1],
          acc[i][2] + bv[jj + 2], acc[i][3] + bv[jj + 3]);
    } else {
      st4(&gb[(size_t)m * 288 + jj],
          acc[i][0] + bg[jj], acc[i][1] + bg[jj + 1],
          acc[i][2] + bg[jj + 2], acc[i][3] + bg[jj + 3]);
    }
  }
}

// ---------------- kernel 3: QK^T + bias + softmax -> P chunk (16 l-rows) ----------------
// block=(b,h); P chunk layout [lc][h][b][kk]
__global__ __launch_bounds__(256) void k_att(const bf16* __restrict__ qkb,
                                             const float* __restrict__ bias_t,
                                             bf16* __restrict__ Pb, int l0) {
  __shared__ float Qs[16 * 24];
  __shared__ float Ks[24 * 196];
  __shared__ float S[16 * 196];
  int t = threadIdx.x;
  int bq = blockIdx.x, h = blockIdx.y;
  for (int u = t; u < 48; u += 256) {
    int r = u / 3, j = u % 3;
    float f[8];
    ld8(&qkb[(size_t)(bq * 192 + l0 + r) * 576 + h * 24 + j * 8], f);
#pragma unroll
    for (int i = 0; i < 8; ++i) Qs[r * 24 + j * 8 + i] = f[i];
  }
  for (int u = t; u < 576; u += 256) {
    int kk = u / 3, j = u % 3;
    float f[8];
    ld8(&qkb[(size_t)(kk * 192 + bq) * 576 + 288 + h * 24 + j * 8], f);
#pragma unroll
    for (int i = 0; i < 8; ++i) Ks[(j * 8 + i) * 196 + kk] = f[i];
  }
  __syncthreads();
  int tx = t & 15, ty = t >> 4;
  float acc[12] = {};
#pragma unroll 4
  for (int c = 0; c < 24; ++c) {
    float q = Qs[ty * 24 + c];
    float kv[12];
    *reinterpret_cast<float4*>(&kv[0]) = *reinterpret_cast<const float4*>(&Ks[c * 196 + tx * 12]);
    *reinterpret_cast<float4*>(&kv[4]) = *reinterpret_cast<const float4*>(&Ks[c * 196 + tx * 12 + 4]);
    *reinterpret_cast<float4*>(&kv[8]) = *reinterpret_cast<const float4*>(&Ks[c * 196 + tx * 12 + 8]);
#pragma unroll
    for (int j = 0; j < 12; ++j) acc[j] += q * kv[j];
  }
  const float sq_c = 0.20412414523193154f;  // 1/sqrt(24)
  int l = l0 + ty;
  float bia[12];
  *reinterpret_cast<float4*>(&bia[0]) = *reinterpret_cast<const float4*>(&bias_t[(size_t)h * LL + (size_t)l * 192 + tx * 12]);
  *reinterpret_cast<float4*>(&bia[4]) = *reinterpret_cast<const float4*>(&bias_t[(size_t)h * LL + (size_t)l * 192 + tx * 12 + 4]);
  *reinterpret_cast<float4*>(&bia[8]) = *reinterpret_cast<const float4*>(&bias_t[(size_t)h * LL + (size_t)l * 192 + tx * 12 + 8]);
#pragma unroll
  for (int j = 0; j < 12; ++j) S[ty * 196 + tx * 12 + j] = acc[j] * sq_c + bia[j];
  __syncthreads();
  int wv = t >> 6, lane = t & 63;
#pragma unroll
  for (int i = 0; i < 4; ++i) {
    int r = wv * 4 + i;
    float s0 = S[r * 196 + lane];
    float s1 = S[r * 196 + lane + 64];
    float s2 = S[r * 196 + lane + 128];
    float mx = wave_max(fmaxf(s0, fmaxf(s1, s2)));
    float e0 = __expf(s0 - mx), e1 = __expf(s1 - mx), e2 = __expf(s2 - mx);
    float inv = 1.0f / wave_sum(e0 + e1 + e2);
    size_t base = (((size_t)r * 12 + h) * 192 + bq) * 192;
    Pb[base + lane] = __float2bfloat16(e0 * inv);
    Pb[base + lane + 64] = __float2bfloat16(e1 * inv);
    Pb[base + lane + 128] = __float2bfloat16(e2 * inv);
  }
}

// ---------------- kernel 4: O = P @ V + sigmoid gate (chunked) ----------------
// block=(lc, h, bs); each handles 64 b-rows x 24 c
__global__ __launch_bounds__(256) void k_pv(const bf16* __restrict__ Pb,
                                            const bf16* __restrict__ vb,
                                            const bf16* __restrict__ gb,
                                            bf16* __restrict__ ogb, int l0) {
  __shared__ float Vs[192 * 24];
  __shared__ float Ps[64 * 68];
  int t = threadIdx.x;
  int lc = blockIdx.x, h = blockIdx.y, bs = blockIdx.z;
  int l = l0 + lc;
  const bf16* vsrc = &vb[((size_t)l * 12 + h) * 4608];
  for (int u = t; u < 576; u += 256) {
    float f[8];
    ld8(&vsrc[u * 8], f);
#pragma unroll
    for (int i = 0; i < 8; ++i) Vs[u * 8 + i] = f[i];
  }
  const bf16* psrc = &Pb[(((size_t)lc * 12 + h) * 192 + bs * 64) * 192];
  int tx = t & 3, ty = t >> 2;
  float acc[6] = {};
  for (int kc = 0; kc < 3; ++kc) {
    __syncthreads();
#pragma unroll
    for (int ii = 0; ii < 2; ++ii) {
      int u = t + ii * 256;            // u in [0,512)
      int b2 = u >> 3, kq8 = (u & 7) * 8;
      float f[8];
      ld8(&psrc[(size_t)b2 * 192 + kc * 64 + kq8], f);
#pragma unroll
      for (int i = 0; i < 8; ++i) Ps[b2 * 68 + kq8 + i] = f[i];
    }
    __syncthreads();
#pragma unroll 8
    for (int kq = 0; kq < 64; ++kq) {
      int kkg = kc * 64 + kq;
      float vv[6];
      *reinterpret_cast<float2*>(&vv[0]) = *reinterpret_cast<const float2*>(&Vs[kkg * 24 + tx * 6]);
      *reinterpret_cast<float2*>(&vv[2]) = *reinterpret_cast<const float2*>(&Vs[kkg * 24 + tx * 6 + 2]);
      *reinterpret_cast<float2*>(&vv[4]) = *reinterpret_cast<const float2*>(&Vs[kkg * 24 + tx * 6 + 4]);
      float p = Ps[ty * 68 + kq];
#pragma unroll
      for (int j = 0; j < 6; ++j) acc[j] += p * vv[j];
    }
  }
  int b = bs * 64 + ty;
  size_t m = (size_t)b * 192 + l;
#pragma unroll
  for (int j = 0; j < 6; ++j) {
    int cc = tx * 6 + j;
    float gv = bf2f(*reinterpret_cast<const u16*>(&gb[m * 288 + h * 24 + cc]));
    float sg = 1.0f / (1.0f + __expf(-gv));
    ogb[m * 288 + h * 24 + cc] = __float2bfloat16(acc[j] * sg);
  }
}

// ---------------- kernel 5: out = o_g @ Wo + bo (f32 out) ----------------
__global__ __launch_bounds__(256) void k_out(const bf16* __restrict__ ogb,
                                             const float* __restrict__ Wo,
                                             const float* __restrict__ bo,
                                             float* __restrict__ out) {
  __shared__ float As[72 * 68];  // [k][m]
  __shared__ float Bs[72 * 68];  // [k][n]
  int t = threadIdx.x;
  int m0 = blockIdx.x * 64, n0 = blockIdx.y * 64;
  int tx = t & 15, ty = t >> 4;
  float acc[4][4] = {};
  for (int kc = 0; kc < 4; ++kc) {
    __syncthreads();
    for (int u = t; u < 576; u += 256) {
      int r = u / 9, j = u % 9;
      float f[8];
      ld8(&ogb[(size_t)(m0 + r) * 288 + kc * 72 + j * 8], f);
#pragma unroll
      for (int i = 0; i < 8; ++i) As[(j * 8 + i) * 68 + r] = f[i];
    }
    for (int f = t; f < 4608; f += 256) {
      int kr = f >> 6, n = f & 63;
      Bs[kr * 68 + n] = Wo[(size_t)(kc * 72 + kr) * 128 + n0 + n];
    }
    __syncthreads();
#pragma unroll 8
    for (int k = 0; k < 72; ++k) {
      float4 a = *reinterpret_cast<const float4*>(&As[k * 68 + ty * 4]);
      float4 b4 = *reinterpret_cast<const float4*>(&Bs[k * 68 + tx * 4]);
      float av[4] = {a.x, a.y, a.z, a.w};
      float bvv[4] = {b4.x, b4.y, b4.z, b4.w};
#pragma unroll
      for (int i = 0; i < 4; ++i)
#pragma unroll
        for (int j = 0; j < 4; ++j) acc[i][j] += av[i] * bvv[j];
    }
  }
#pragma unroll
  for (int i = 0; i < 4; ++i) {
    int m = m0 + ty * 4 + i;
#pragma unroll
    for (int j = 0; j < 4; ++j) {
      int d = n0 + tx * 4 + j;
      out[(size_t)m * 128 + d] = acc[i][j] + bo[d];
    }
  }
}

extern "C" void kernel_launch(void* const* d_in, const int* in_sizes, int n_in,
                              void* d_out, int out_size, void* d_ws, size_t ws_size,
                              hipStream_t stream) {
  const float* z_in = (const float*)d_in[0];
  const float* ln_w = (const float*)d_in[1];
  const float* ln_b = (const float*)d_in[2];
  const float* Wq   = (const float*)d_in[3];
  const float* bq   = (const float*)d_in[4];
  const float* Wk   = (const float*)d_in[5];
  const float* bk   = (const float*)d_in[6];
  const float* Wv   = (const float*)d_in[7];
  const float* bv   = (const float*)d_in[8];
  const float* Wb   = (const float*)d_in[9];
  const float* bb   = (const float*)d_in[10];
  const float* Wg   = (const float*)d_in[11];
  const float* bg   = (const float*)d_in[12];
  const float* Wo   = (const float*)d_in[13];
  const float* bo   = (const float*)d_in[14];
  float* out = (float*)d_out;

  // workspace layout (bytes); total = 122,093,568 (~116.4 MiB)
  char* ws = (char*)d_ws;
  bf16* zb    = (bf16*)ws;                      // [36864][128] bf16 (9.4 MB)
  bf16* ogb   = (bf16*)ws;                      // UNION with zb: [36864][288] bf16 (21.2 MB); zb dead first
  bf16* qkb   = (bf16*)(ws + 21233664);         // [36864][576] q|k (42.5 MB)
  bf16* vb    = (bf16*)(ws + 63700992);         // [192][12][192][24] (21.2 MB)
  bf16* gb    = (bf16*)(ws + 84934656);         // [36864][288] (21.2 MB)
  float* biasb = (float*)(ws + 106168320);      // [12][192][192] f32 (1.77 MB)
  bf16* Pb    = (bf16*)(ws + 107937792);        // [16][12][192][192] chunk (14.2 MB)

  k_ln<<<dim3(9216), dim3(256), 0, stream>>>(z_in, ln_w, ln_b, zb);
  k_biasproj<<<dim3(9216), dim3(256), 0, stream>>>(zb, Wb, bb, biasb);
  k_proj<<<dim3(576, 18), dim3(256), 0, stream>>>(zb, Wq, bq, Wk, bk, Wv, bv, Wg, bg,
                                                  qkb, vb, gb);
  for (int l0 = 0; l0 < 192; l0 += 16) {
    k_att<<<dim3(192, 12), dim3(256), 0, stream>>>(qkb, biasb, Pb, l0);
    k_pv<<<dim3(16, 12, 3), dim3(256), 0, stream>>>(Pb, vb, gb, ogb, l0);
  }
  k_out<<<dim3(576, 2), dim3(256), 0, stream>>>(ogb, Wo, bo, out);
}

// Round 3
// 403.478 us; speedup vs baseline: 1.7280x; 1.7280x over previous
//
#include <hip/hip_runtime.h>
#include <hip/hip_bf16.h>
#include <math.h>

typedef __hip_bfloat16 bf16;
typedef unsigned short u16;
typedef unsigned int u32;
typedef __attribute__((ext_vector_type(8))) short bf16x8;
typedef __attribute__((ext_vector_type(4))) float f32x4;

#define LL 36864  // L*L

__device__ __forceinline__ float wave_sum(float v) {
#pragma unroll
  for (int m = 32; m; m >>= 1) v += __shfl_xor(v, m, 64);
  return v;
}

__device__ __forceinline__ float bf2f(u16 u) {
  union { float f; u32 u; } c; c.u = ((u32)u) << 16; return c.f;
}
__device__ __forceinline__ u16 f2bf(float f) {  // RNE
  union { float f; u32 u; } c; c.f = f;
  u32 r = c.u + 0x7fffu + ((c.u >> 16) & 1u);
  return (u16)(r >> 16);
}

// ---------------- kernel 0a: convert Wq|Wk|Wv|Wg -> Wcat_t[jg][128] bf16 ----------------
__global__ __launch_bounds__(256) void k_cvt(const float* __restrict__ Wq,
                                             const float* __restrict__ Wk,
                                             const float* __restrict__ Wv,
                                             const float* __restrict__ Wg,
                                             bf16* __restrict__ Wcat) {
  int u = blockIdx.x * 256 + threadIdx.x;   // 18432 tasks
  if (u >= 18432) return;
  int jg = u >> 4, k0 = (u & 15) * 8;
  int sec = jg / 288, j = jg % 288;
  const float* W = sec == 0 ? Wq : sec == 1 ? Wk : sec == 2 ? Wv : Wg;
  u16 pk[8];
#pragma unroll
  for (int i = 0; i < 8; ++i) pk[i] = f2bf(W[(size_t)(k0 + i) * 288 + j]);
  *reinterpret_cast<uint4*>(&Wcat[(size_t)jg * 128 + k0]) = *reinterpret_cast<uint4*>(pk);
}

// ---------------- kernel 0b: convert Wo -> Wot[n][288] bf16 (runs late) ----------------
__global__ __launch_bounds__(256) void k_cvt2(const float* __restrict__ Wo,
                                              bf16* __restrict__ Wot) {
  int u = blockIdx.x * 256 + threadIdx.x;   // 4608 tasks
  if (u >= 4608) return;
  int n = u / 36, k0 = (u % 36) * 8;
  u16 pk[8];
#pragma unroll
  for (int i = 0; i < 8; ++i) pk[i] = f2bf(Wo[(size_t)(k0 + i) * 128 + n]);
  *reinterpret_cast<uint4*>(&Wot[(size_t)n * 288 + k0]) = *reinterpret_cast<uint4*>(pk);
}

// ---------------- kernel 1: LayerNorm f32 -> bf16 ----------------
__global__ __launch_bounds__(256) void k_ln(const float* __restrict__ zin,
                                            const float* __restrict__ w,
                                            const float* __restrict__ b,
                                            bf16* __restrict__ zb) {
  int t = threadIdx.x;
  int wv = t >> 6, lane = t & 63;
  size_t m = (size_t)blockIdx.x * 4 + wv;
  const float2 v = *reinterpret_cast<const float2*>(&zin[m * 128 + lane * 2]);
  float s = wave_sum(v.x + v.y);
  float ss = wave_sum(v.x * v.x + v.y * v.y);
  float mean = s * (1.0f / 128.0f);
  float var = ss * (1.0f / 128.0f) - mean * mean;
  float rs = rsqrtf(var + 1e-5f);
  float o0 = (v.x - mean) * rs * w[lane * 2] + b[lane * 2];
  float o1 = (v.y - mean) * rs * w[lane * 2 + 1] + b[lane * 2 + 1];
  u32 pk = (u32)f2bf(o0) | ((u32)f2bf(o1) << 16);
  *reinterpret_cast<u32*>(&zb[m * 128 + lane * 2]) = pk;
}

// ---------------- kernel 1b: bias projection ----------------
// biasb[h][l][kk] = (z[m]@Wb)[h] + bb[h],  m = kk*192 + l
__global__ __launch_bounds__(256) void k_biasproj(const bf16* __restrict__ zb,
                                                  const float* __restrict__ Wb,
                                                  const float* __restrict__ bbv,
                                                  float* __restrict__ biasb) {
  int t = threadIdx.x;
  int wv = t >> 6, lane = t & 63;
  int m = blockIdx.x * 4 + wv;
  u32 pk = *reinterpret_cast<const u32*>(&zb[(size_t)m * 128 + lane * 2]);
  float z0 = bf2f((u16)(pk & 0xffff)), z1 = bf2f((u16)(pk >> 16));
  float acc[12];
#pragma unroll
  for (int h = 0; h < 12; ++h)
    acc[h] = z0 * Wb[(lane * 2) * 12 + h] + z1 * Wb[(lane * 2 + 1) * 12 + h];
#pragma unroll
  for (int h = 0; h < 12; ++h) acc[h] = wave_sum(acc[h]);
  if (lane == 0) {
    int kk = m / 192, l = m % 192;
#pragma unroll
    for (int h = 0; h < 12; ++h)
      biasb[(size_t)h * LL + (size_t)l * 192 + kk] = acc[h] + bbv[h];
  }
}

// ---------------- kernel 2: q,k,v,g projections (MFMA) ----------------
// zb[m][128] @ Wcat_t -> head-grouped layouts:
// q2[((mhigh*12+h)*192+mlow)*24+c] ; k2/vb/g2[((mlow*12+h)*192+mhigh)*24+c]
__global__ __launch_bounds__(256) void k_proj(const bf16* __restrict__ zb,
    const bf16* __restrict__ Wcat,
    const float* __restrict__ bq, const float* __restrict__ bk,
    const float* __restrict__ bv, const float* __restrict__ bg,
    bf16* __restrict__ q2, bf16* __restrict__ k2,
    bf16* __restrict__ vb, bf16* __restrict__ g2) {
  int t = threadIdx.x;
  int w = t >> 6, lane = t & 63;
  int c15 = lane & 15, g = lane >> 4;
  int m0 = blockIdx.x * 128, n0 = blockIdx.y * 128;
  f32x4 acc[2][8];
#pragma unroll
  for (int mt = 0; mt < 2; ++mt)
#pragma unroll
    for (int nt = 0; nt < 8; ++nt) acc[mt][nt] = (f32x4){0.f, 0.f, 0.f, 0.f};
#pragma unroll
  for (int kt = 0; kt < 4; ++kt) {
    bf16x8 a[2], b[8];
#pragma unroll
    for (int mt = 0; mt < 2; ++mt)
      a[mt] = *reinterpret_cast<const bf16x8*>(
          &zb[(size_t)(m0 + (w * 2 + mt) * 16 + c15) * 128 + kt * 32 + g * 8]);
#pragma unroll
    for (int nt = 0; nt < 8; ++nt)
      b[nt] = *reinterpret_cast<const bf16x8*>(
          &Wcat[(size_t)(n0 + nt * 16 + c15) * 128 + kt * 32 + g * 8]);
#pragma unroll
    for (int mt = 0; mt < 2; ++mt)
#pragma unroll
      for (int nt = 0; nt < 8; ++nt)
        acc[mt][nt] = __builtin_amdgcn_mfma_f32_16x16x32_bf16(a[mt], b[nt], acc[mt][nt], 0, 0, 0);
  }
#pragma unroll
  for (int mt = 0; mt < 2; ++mt) {
    int mbase = m0 + (w * 2 + mt) * 16 + 4 * g;
#pragma unroll
    for (int nt = 0; nt < 8; ++nt) {
      int jg = n0 + nt * 16 + c15;
      int sec = jg / 288, j = jg % 288;
      int h = j / 24, c = j % 24;
      const float* barr = sec == 0 ? bq : sec == 1 ? bk : sec == 2 ? bv : bg;
      float bval = barr[j];
      bf16* dst = sec == 0 ? q2 : sec == 1 ? k2 : sec == 2 ? vb : g2;
#pragma unroll
      for (int i = 0; i < 4; ++i) {
        int m = mbase + i;
        int mh = m / 192, ml = m % 192;
        size_t addr;
        if (sec == 0) addr = ((size_t)(mh * 12 + h) * 192 + ml) * 24 + c;
        else          addr = ((size_t)(ml * 12 + h) * 192 + mh) * 24 + c;
        *reinterpret_cast<u16*>(&dst[addr]) = f2bf(acc[mt][nt][i] + bval);
      }
    }
  }
}

// ---------------- kernel 3: QK^T + bias + softmax -> P chunk (MFMA) ----------------
// wave = (bq, h); 16 l-rows x 192 kk. P layout [lc][h][b][kk]
__global__ __launch_bounds__(256) void k_att(const bf16* __restrict__ q2,
                                             const bf16* __restrict__ k2,
                                             const float* __restrict__ biasb,
                                             bf16* __restrict__ Pb, int l0) {
  __shared__ u16 Sb[4][16 * 200];
  int t = threadIdx.x;
  int w = t >> 6, lane = t & 63;
  int c15 = lane & 15, g = lane >> 4;
  int bq = blockIdx.x * 4 + w, h = blockIdx.y;
  const bf16* qs = &q2[(((size_t)bq * 12 + h) * 192 + l0) * 24];
  const bf16* ks = &k2[((size_t)bq * 12 + h) * 4608];
  bf16x8 afr = {0, 0, 0, 0, 0, 0, 0, 0};
  if (g < 3) afr = *reinterpret_cast<const bf16x8*>(&qs[c15 * 24 + g * 8]);
  f32x4 acc[12];
#pragma unroll
  for (int ct = 0; ct < 12; ++ct) {
    bf16x8 bfr = {0, 0, 0, 0, 0, 0, 0, 0};
    if (g < 3) bfr = *reinterpret_cast<const bf16x8*>(&ks[(ct * 16 + c15) * 24 + g * 8]);
    acc[ct] = __builtin_amdgcn_mfma_f32_16x16x32_bf16(afr, bfr, (f32x4){0.f, 0.f, 0.f, 0.f}, 0, 0, 0);
  }
  const float sq_c = 0.20412414523193154f;  // 1/sqrt(24)
  // scale + bias
#pragma unroll
  for (int i = 0; i < 4; ++i) {
    int l = l0 + 4 * g + i;
#pragma unroll
    for (int ct = 0; ct < 12; ++ct)
      acc[ct][i] = acc[ct][i] * sq_c + biasb[(size_t)h * LL + (size_t)l * 192 + ct * 16 + c15];
  }
  // softmax over kk (ct in-reg x c15 via shfl)
  float inv[4];
#pragma unroll
  for (int i = 0; i < 4; ++i) {
    float mx = -1e30f;
#pragma unroll
    for (int ct = 0; ct < 12; ++ct) mx = fmaxf(mx, acc[ct][i]);
#pragma unroll
    for (int msk = 1; msk < 16; msk <<= 1) mx = fmaxf(mx, __shfl_xor(mx, msk, 64));
    float sm = 0.f;
#pragma unroll
    for (int ct = 0; ct < 12; ++ct) {
      float e = __expf(acc[ct][i] - mx);
      acc[ct][i] = e;
      sm += e;
    }
#pragma unroll
    for (int msk = 1; msk < 16; msk <<= 1) sm += __shfl_xor(sm, msk, 64);
    inv[i] = 1.0f / sm;
  }
  // bounce to LDS (per-wave), then coalesced global write
#pragma unroll
  for (int i = 0; i < 4; ++i)
#pragma unroll
    for (int ct = 0; ct < 12; ++ct)
      Sb[w][(4 * g + i) * 200 + ct * 16 + c15] = f2bf(acc[ct][i] * inv[i]);
  __syncthreads();
  for (int u = lane; u < 384; u += 64) {
    int lloc = u / 24, oct = u % 24;
    uint4 val = *reinterpret_cast<const uint4*>(&Sb[w][lloc * 200 + oct * 8]);
    *reinterpret_cast<uint4*>(
        &Pb[(((size_t)lloc * 12 + h) * 192 + bq) * 192 + oct * 8]) = val;
  }
}

// ---------------- kernel 4: O = P @ V_l + sigmoid gate (MFMA) ----------------
// block=(lc, h): A = P[b][kk] direct from global; B = V_l^T staged in LDS
__global__ __launch_bounds__(256) void k_pv(const bf16* __restrict__ Pb,
                                            const bf16* __restrict__ vb,
                                            const bf16* __restrict__ g2,
                                            bf16* __restrict__ ogb, int l0) {
  __shared__ u16 Vt[32 * 200];   // [c][kk], stride 200
  __shared__ float Ob[192 * 26]; // [b][c], stride 26
  int t = threadIdx.x;
  int w = t >> 6, lane = t & 63;
  int c15 = lane & 15, g = lane >> 4;
  int lc = blockIdx.x, h = blockIdx.y;
  int l = l0 + lc;
  const bf16* vs = &vb[((size_t)l * 12 + h) * 4608];
  for (int u = t; u < 576; u += 256) {
    int kk = u / 3, c0 = (u % 3) * 8;
    uint4 val = *reinterpret_cast<const uint4*>(&vs[kk * 24 + c0]);
    const u16* pv = reinterpret_cast<const u16*>(&val);
#pragma unroll
    for (int i = 0; i < 8; ++i) Vt[(c0 + i) * 200 + kk] = pv[i];
  }
  for (int u = t; u < 8 * 200; u += 256) Vt[(24 + u / 200) * 200 + (u % 200)] = 0;
  __syncthreads();
  const bf16* Ps = &Pb[((size_t)lc * 12 + h) * 36864];
  f32x4 acc[3][2];
#pragma unroll
  for (int bt = 0; bt < 3; ++bt)
#pragma unroll
    for (int nt = 0; nt < 2; ++nt) acc[bt][nt] = (f32x4){0.f, 0.f, 0.f, 0.f};
#pragma unroll
  for (int kt = 0; kt < 6; ++kt) {
    bf16x8 a[3], b[2];
#pragma unroll
    for (int bt = 0; bt < 3; ++bt)
      a[bt] = *reinterpret_cast<const bf16x8*>(
          &Ps[(size_t)((w * 3 + bt) * 16 + c15) * 192 + kt * 32 + g * 8]);
#pragma unroll
    for (int nt = 0; nt < 2; ++nt)
      b[nt] = *reinterpret_cast<const bf16x8*>(
          reinterpret_cast<const u16*>(Vt) + (nt * 16 + c15) * 200 + kt * 32 + g * 8);
#pragma unroll
    for (int bt = 0; bt < 3; ++bt)
#pragma unroll
      for (int nt = 0; nt < 2; ++nt)
        acc[bt][nt] = __builtin_amdgcn_mfma_f32_16x16x32_bf16(a[bt], b[nt], acc[bt][nt], 0, 0, 0);
  }
#pragma unroll
  for (int bt = 0; bt < 3; ++bt)
#pragma unroll
    for (int nt = 0; nt < 2; ++nt)
#pragma unroll
      for (int i = 0; i < 4; ++i) {
        int b = (w * 3 + bt) * 16 + 4 * g + i;
        int c = nt * 16 + c15;
        if (c < 24) Ob[b * 26 + c] = acc[bt][nt][i];
      }
  __syncthreads();
  for (int u = t; u < 576; u += 256) {
    int b = u / 3, c0 = (u % 3) * 8;
    size_t m = (size_t)b * 192 + l;
    uint4 gv4 = *reinterpret_cast<const uint4*>(&g2[(((size_t)l * 12 + h) * 192 + b) * 24 + c0]);
    const u16* gp = reinterpret_cast<const u16*>(&gv4);
    u16 opk[8];
#pragma unroll
    for (int i = 0; i < 8; ++i) {
      float gv = bf2f(gp[i]);
      float sg = 1.0f / (1.0f + __expf(-gv));
      opk[i] = f2bf(Ob[b * 26 + c0 + i] * sg);
    }
    *reinterpret_cast<uint4*>(&ogb[m * 288 + h * 24 + c0]) = *reinterpret_cast<uint4*>(opk);
  }
}

// ---------------- kernel 5: out = ogb @ Wo + bo (MFMA, f32 out) ----------------
__global__ __launch_bounds__(256) void k_out(const bf16* __restrict__ ogb,
                                             const bf16* __restrict__ Wot,
                                             const float* __restrict__ bo,
                                             float* __restrict__ out) {
  int t = threadIdx.x;
  int w = t >> 6, lane = t & 63;
  int c15 = lane & 15, g = lane >> 4;
  int m0 = blockIdx.x * 128;
  f32x4 acc[2][8];
#pragma unroll
  for (int mt = 0; mt < 2; ++mt)
#pragma unroll
    for (int nt = 0; nt < 8; ++nt) acc[mt][nt] = (f32x4){0.f, 0.f, 0.f, 0.f};
#pragma unroll
  for (int kt = 0; kt < 9; ++kt) {
    bf16x8 a[2], b[8];
#pragma unroll
    for (int mt = 0; mt < 2; ++mt)
      a[mt] = *reinterpret_cast<const bf16x8*>(
          &ogb[(size_t)(m0 + (w * 2 + mt) * 16 + c15) * 288 + kt * 32 + g * 8]);
#pragma unroll
    for (int nt = 0; nt < 8; ++nt)
      b[nt] = *reinterpret_cast<const bf16x8*>(
          &Wot[(size_t)(nt * 16 + c15) * 288 + kt * 32 + g * 8]);
#pragma unroll
    for (int mt = 0; mt < 2; ++mt)
#pragma unroll
      for (int nt = 0; nt < 8; ++nt)
        acc[mt][nt] = __builtin_amdgcn_mfma_f32_16x16x32_bf16(a[mt], b[nt], acc[mt][nt], 0, 0, 0);
  }
#pragma unroll
  for (int mt = 0; mt < 2; ++mt)
#pragma unroll
    for (int nt = 0; nt < 8; ++nt) {
      int n = nt * 16 + c15;
      float bval = bo[n];
#pragma unroll
      for (int i = 0; i < 4; ++i) {
        int m = m0 + (w * 2 + mt) * 16 + 4 * g + i;
        out[(size_t)m * 128 + n] = acc[mt][nt][i] + bval;
      }
    }
}

extern "C" void kernel_launch(void* const* d_in, const int* in_sizes, int n_in,
                              void* d_out, int out_size, void* d_ws, size_t ws_size,
                              hipStream_t stream) {
  const float* z_in = (const float*)d_in[0];
  const float* ln_w = (const float*)d_in[1];
  const float* ln_b = (const float*)d_in[2];
  const float* Wq   = (const float*)d_in[3];
  const float* bq   = (const float*)d_in[4];
  const float* Wk   = (const float*)d_in[5];
  const float* bk   = (const float*)d_in[6];
  const float* Wv   = (const float*)d_in[7];
  const float* bv   = (const float*)d_in[8];
  const float* Wb   = (const float*)d_in[9];
  const float* bb   = (const float*)d_in[10];
  const float* Wg   = (const float*)d_in[11];
  const float* bg   = (const float*)d_in[12];
  const float* Wo   = (const float*)d_in[13];
  const float* bo   = (const float*)d_in[14];
  float* out = (float*)d_out;

  // workspace layout (bytes), total = 122,093,568 (same as proven round-2)
  char* ws = (char*)d_ws;
  bf16* ogb   = (bf16*)ws;                   // [36864][288] bf16 (written by k_pv)
  bf16* zb    = (bf16*)ws;                   // union: [36864][128] bf16 (dead after k_proj)
  bf16* Wcat  = (bf16*)(ws + 9437184);       // [1152][128] bf16 (inside ogb region; dead after k_proj)
  bf16* q2    = (bf16*)(ws + 21233664);      // [b][h][l][24] bf16
  bf16* Wot   = (bf16*)(ws + 21233664);      // union with q2: [128][288] bf16 (written after att loop)
  bf16* k2    = (bf16*)(ws + 42467328);      // [b][h][kk][24]
  bf16* vb    = (bf16*)(ws + 63700992);      // [l][h][kk][24]
  bf16* g2    = (bf16*)(ws + 84934656);      // [l][h][b][24]
  float* biasb = (float*)(ws + 106168320);   // [12][192][192] f32
  bf16* Pb    = (bf16*)(ws + 107937792);     // [16][12][192][192] bf16 chunk

  k_cvt<<<dim3(72), dim3(256), 0, stream>>>(Wq, Wk, Wv, Wg, Wcat);
  k_ln<<<dim3(9216), dim3(256), 0, stream>>>(z_in, ln_w, ln_b, zb);
  k_biasproj<<<dim3(9216), dim3(256), 0, stream>>>(zb, Wb, bb, biasb);
  k_proj<<<dim3(288, 9), dim3(256), 0, stream>>>(zb, Wcat, bq, bk, bv, bg,
                                                 q2, k2, vb, g2);
  for (int l0 = 0; l0 < 192; l0 += 16) {
    k_att<<<dim3(48, 12), dim3(256), 0, stream>>>(q2, k2, biasb, Pb, l0);
    k_pv<<<dim3(16, 12), dim3(256), 0, stream>>>(Pb, vb, g2, ogb, l0);
  }
  k_cvt2<<<dim3(18), dim3(256), 0, stream>>>(Wo, Wot);
  k_out<<<dim3(288), dim3(256), 0, stream>>>(ogb, Wot, bo, out);
}

// Round 4
// 298.148 us; speedup vs baseline: 2.3385x; 1.3533x over previous
//
#include <hip/hip_runtime.h>
#include <hip/hip_bf16.h>
#include <math.h>

typedef __hip_bfloat16 bf16;
typedef unsigned short u16;
typedef unsigned int u32;
typedef __attribute__((ext_vector_type(8))) short bf16x8;
typedef __attribute__((ext_vector_type(4))) float f32x4;

#define LL 36864  // L*L

__device__ __forceinline__ float wave_sum(float v) {
#pragma unroll
  for (int m = 32; m; m >>= 1) v += __shfl_xor(v, m, 64);
  return v;
}

__device__ __forceinline__ float bf2f(u16 u) {
  union { float f; u32 u; } c; c.u = ((u32)u) << 16; return c.f;
}
__device__ __forceinline__ u16 f2bf(float f) {  // RNE
  union { float f; u32 u; } c; c.f = f;
  u32 r = c.u + 0x7fffu + ((c.u >> 16) & 1u);
  return (u16)(r >> 16);
}

// ---------------- kernel 0a: Wq|Wk|Wv|Wg -> Wcat[jg][128] bf16 ----------------
__global__ __launch_bounds__(256) void k_cvt(const float* __restrict__ Wq,
                                             const float* __restrict__ Wk,
                                             const float* __restrict__ Wv,
                                             const float* __restrict__ Wg,
                                             bf16* __restrict__ Wcat) {
  int u = blockIdx.x * 256 + threadIdx.x;   // 18432 tasks
  if (u >= 18432) return;
  int jg = u >> 4, k0 = (u & 15) * 8;
  int sec = jg / 288, j = jg % 288;
  const float* W = sec == 0 ? Wq : sec == 1 ? Wk : sec == 2 ? Wv : Wg;
  u16 pk[8];
#pragma unroll
  for (int i = 0; i < 8; ++i) pk[i] = f2bf(W[(size_t)(k0 + i) * 288 + j]);
  *reinterpret_cast<uint4*>(&Wcat[(size_t)jg * 128 + k0]) = *reinterpret_cast<uint4*>(pk);
}

// ---------------- kernel 0b: Wo -> Wot[n][288] bf16 ----------------
__global__ __launch_bounds__(256) void k_cvt2(const float* __restrict__ Wo,
                                              bf16* __restrict__ Wot) {
  int u = blockIdx.x * 256 + threadIdx.x;   // 4608 tasks
  if (u >= 4608) return;
  int n = u / 36, k0 = (u % 36) * 8;
  u16 pk[8];
#pragma unroll
  for (int i = 0; i < 8; ++i) pk[i] = f2bf(Wo[(size_t)(k0 + i) * 128 + n]);
  *reinterpret_cast<uint4*>(&Wot[(size_t)n * 288 + k0]) = *reinterpret_cast<uint4*>(pk);
}

// ---------------- kernel 1: LayerNorm + fused bias projection ----------------
__global__ __launch_bounds__(256) void k_ln(const float* __restrict__ zin,
                                            const float* __restrict__ w_,
                                            const float* __restrict__ b_,
                                            const float* __restrict__ Wb,
                                            const float* __restrict__ bbv,
                                            bf16* __restrict__ zb,
                                            float* __restrict__ biasb) {
  int t = threadIdx.x;
  int wv = t >> 6, lane = t & 63;
  size_t m = (size_t)blockIdx.x * 4 + wv;
  const float2 v = *reinterpret_cast<const float2*>(&zin[m * 128 + lane * 2]);
  float s = wave_sum(v.x + v.y);
  float ss = wave_sum(v.x * v.x + v.y * v.y);
  float mean = s * (1.0f / 128.0f);
  float var = ss * (1.0f / 128.0f) - mean * mean;
  float rs = rsqrtf(var + 1e-5f);
  float o0 = (v.x - mean) * rs * w_[lane * 2] + b_[lane * 2];
  float o1 = (v.y - mean) * rs * w_[lane * 2 + 1] + b_[lane * 2 + 1];
  u32 pk = (u32)f2bf(o0) | ((u32)f2bf(o1) << 16);
  *reinterpret_cast<u32*>(&zb[m * 128 + lane * 2]) = pk;
  // fused bias projection: biasb[h][l][kk] = z[m] @ Wb + bb, m = kk*192 + l
  float accb[12];
#pragma unroll
  for (int h = 0; h < 12; ++h)
    accb[h] = o0 * Wb[(lane * 2) * 12 + h] + o1 * Wb[(lane * 2 + 1) * 12 + h];
#pragma unroll
  for (int h = 0; h < 12; ++h) accb[h] = wave_sum(accb[h]);
  if (lane == 0) {
    int kk = (int)m / 192, l = (int)m % 192;
#pragma unroll
    for (int h = 0; h < 12; ++h)
      biasb[(size_t)h * LL + (size_t)l * 192 + kk] = accb[h] + bbv[h];
  }
}

// ---------------- kernel 2: projections (MFMA, 192x96 tiles, LDS-bounced stores) ----
// grid (192, 12): y -> sec = y/3, 4 heads h0=(y%3)*4, 96 cols.
// outputs: q2[b][h][l][c], k2[b][h][kk][c], vb[l][h][kk][c], gbuf[m][288]
__global__ __launch_bounds__(256) void k_proj(const bf16* __restrict__ zb,
    const bf16* __restrict__ Wcat,
    const float* __restrict__ bq, const float* __restrict__ bk,
    const float* __restrict__ bv, const float* __restrict__ bg,
    bf16* __restrict__ q2, bf16* __restrict__ k2,
    bf16* __restrict__ vb, bf16* __restrict__ gbuf) {
  __shared__ __align__(16) u16 Sb[192 * 104];
  int t = threadIdx.x;
  int w = t >> 6, lane = t & 63;
  int c15 = lane & 15, g = lane >> 4;
  int wm = w & 1, wn = w >> 1;
  int bx = blockIdx.x, y = blockIdx.y;
  int sec = y / 3, h0 = (y % 3) * 4;
  int m0 = bx * 192;
  int jbase = y * 96;  // == sec*288 + (y%3)*96
  f32x4 acc[6][3];
#pragma unroll
  for (int mt = 0; mt < 6; ++mt)
#pragma unroll
    for (int nt = 0; nt < 3; ++nt) acc[mt][nt] = (f32x4){0.f, 0.f, 0.f, 0.f};
#pragma unroll
  for (int kt = 0; kt < 4; ++kt) {
    bf16x8 a[6], b[3];
#pragma unroll
    for (int mt = 0; mt < 6; ++mt)
      a[mt] = *reinterpret_cast<const bf16x8*>(
          &zb[(size_t)(m0 + wm * 96 + mt * 16 + c15) * 128 + kt * 32 + g * 8]);
#pragma unroll
    for (int nt = 0; nt < 3; ++nt)
      b[nt] = *reinterpret_cast<const bf16x8*>(
          &Wcat[(size_t)(jbase + wn * 48 + nt * 16 + c15) * 128 + kt * 32 + g * 8]);
#pragma unroll
    for (int mt = 0; mt < 6; ++mt)
#pragma unroll
      for (int nt = 0; nt < 3; ++nt)
        acc[mt][nt] = __builtin_amdgcn_mfma_f32_16x16x32_bf16(a[mt], b[nt], acc[mt][nt], 0, 0, 0);
  }
  const float* barr = sec == 0 ? bq : sec == 1 ? bk : sec == 2 ? bv : bg;
#pragma unroll
  for (int nt = 0; nt < 3; ++nt) {
    int col = wn * 48 + nt * 16 + c15;
    float bval = barr[(y % 3) * 96 + col];
#pragma unroll
    for (int mt = 0; mt < 6; ++mt) {
      int rbase = wm * 96 + mt * 16 + 4 * g;
#pragma unroll
      for (int i = 0; i < 4; ++i)
        Sb[(rbase + i) * 104 + col] = f2bf(acc[mt][nt][i] + bval);
    }
  }
  __syncthreads();
  if (sec == 0) {
    bf16* dst0 = q2 + ((size_t)bx * 12 + h0) * 4608;
    for (int u = t; u < 2304; u += 256) {
      int hl = u / 576, off = (u % 576) * 8;
      int ml = off / 24, c0 = off % 24;
      uint4 val = *reinterpret_cast<const uint4*>(&Sb[ml * 104 + hl * 24 + c0]);
      *reinterpret_cast<uint4*>(&dst0[(size_t)hl * 4608 + off]) = val;
    }
  } else if (sec == 3) {
    for (int u = t; u < 2304; u += 256) {
      int ml = u / 12, col = (u % 12) * 8;
      uint4 val = *reinterpret_cast<const uint4*>(&Sb[ml * 104 + col]);
      *reinterpret_cast<uint4*>(&gbuf[(size_t)(m0 + ml) * 288 + h0 * 24 + col]) = val;
    }
  } else {
    bf16* dst = (sec == 1) ? k2 : vb;
    for (int u = t; u < 2304; u += 256) {
      int hl = u / 576, off = (u % 576) * 8;
      int ml = off / 24, c0 = off % 24;
      uint4 val = *reinterpret_cast<const uint4*>(&Sb[ml * 104 + hl * 24 + c0]);
      *reinterpret_cast<uint4*>(
          &dst[(((size_t)ml * 12 + h0 + hl) * 192 + bx) * 24 + c0]) = val;
    }
  }
}

// ---------------- kernel 3: fused att(chunk la0) + pv(chunk lp0) ----------------
// z==0: att role, blocks (48,12): wave=(bq,h), 16 l-rows x 192 kk -> Patt
// z==1: pv role, blocks (48,12): (lc,bs) from x, 64 b-rows x 24 c  -> ogb
__global__ __launch_bounds__(256) void k_attpv(const bf16* __restrict__ q2,
    const bf16* __restrict__ k2, const float* __restrict__ biasb,
    const bf16* __restrict__ vbuf, const bf16* __restrict__ gbuf,
    bf16* __restrict__ Patt, const bf16* __restrict__ Ppv,
    bf16* __restrict__ ogb, int la0, int lp0) {
  __shared__ __align__(16) char ldsraw[38912];
  int t = threadIdx.x;
  int w = t >> 6, lane = t & 63;
  int c15 = lane & 15, g = lane >> 4;
  const float sq_c = 0.20412414523193154f;  // 1/sqrt(24)
  if (blockIdx.z == 0) {
    if (la0 < 0) return;
    float* Lb = reinterpret_cast<float*>(ldsraw);                       // [16][192] f32
    u16* Sb = reinterpret_cast<u16*>(ldsraw + 12288) + (size_t)w * 3200; // per-wave [16][200]
    int bq = blockIdx.x * 4 + w, h = blockIdx.y;
    for (int u = t; u < 768; u += 256) {
      int r = u / 48, c4 = (u % 48) * 4;
      *reinterpret_cast<float4*>(&Lb[r * 192 + c4]) =
          *reinterpret_cast<const float4*>(&biasb[(size_t)h * LL + (size_t)(la0 + r) * 192 + c4]);
    }
    __syncthreads();
    const bf16* qs = &q2[(((size_t)bq * 12 + h) * 192 + la0) * 24];
    const bf16* ks = &k2[((size_t)bq * 12 + h) * 4608];
    bf16x8 afr = {0, 0, 0, 0, 0, 0, 0, 0};
    if (g < 3) afr = *reinterpret_cast<const bf16x8*>(&qs[c15 * 24 + g * 8]);
    f32x4 acc[12];
#pragma unroll
    for (int ct = 0; ct < 12; ++ct) {
      bf16x8 bfr = {0, 0, 0, 0, 0, 0, 0, 0};
      if (g < 3) bfr = *reinterpret_cast<const bf16x8*>(&ks[(ct * 16 + c15) * 24 + g * 8]);
      acc[ct] = __builtin_amdgcn_mfma_f32_16x16x32_bf16(afr, bfr, (f32x4){0.f, 0.f, 0.f, 0.f}, 0, 0, 0);
    }
#pragma unroll
    for (int i = 0; i < 4; ++i)
#pragma unroll
      for (int ct = 0; ct < 12; ++ct)
        acc[ct][i] = acc[ct][i] * sq_c + Lb[(4 * g + i) * 192 + ct * 16 + c15];
    float inv[4];
#pragma unroll
    for (int i = 0; i < 4; ++i) {
      float mx = -1e30f;
#pragma unroll
      for (int ct = 0; ct < 12; ++ct) mx = fmaxf(mx, acc[ct][i]);
#pragma unroll
      for (int msk = 1; msk < 16; msk <<= 1) mx = fmaxf(mx, __shfl_xor(mx, msk, 64));
      float sm = 0.f;
#pragma unroll
      for (int ct = 0; ct < 12; ++ct) {
        float e = __expf(acc[ct][i] - mx);
        acc[ct][i] = e;
        sm += e;
      }
#pragma unroll
      for (int msk = 1; msk < 16; msk <<= 1) sm += __shfl_xor(sm, msk, 64);
      inv[i] = 1.0f / sm;
    }
#pragma unroll
    for (int i = 0; i < 4; ++i)
#pragma unroll
      for (int ct = 0; ct < 12; ++ct)
        Sb[(4 * g + i) * 200 + ct * 16 + c15] = f2bf(acc[ct][i] * inv[i]);
    for (int u = lane; u < 384; u += 64) {
      int lloc = u / 24, oct = u % 24;
      uint4 val = *reinterpret_cast<const uint4*>(&Sb[lloc * 200 + oct * 8]);
      *reinterpret_cast<uint4*>(
          &Patt[(((size_t)lloc * 12 + h) * 192 + bq) * 192 + oct * 8]) = val;
    }
  } else {
    if (lp0 < 0) return;
    u16* Vt = reinterpret_cast<u16*>(ldsraw);                 // [32][200] u16
    float* Ob = reinterpret_cast<float*>(ldsraw + 25600);     // [64][26] f32
    int x = blockIdx.x;
    int lc = x & 15, bs = x >> 4, h = blockIdx.y;
    int l = lp0 + lc;
    const bf16* vs = &vbuf[((size_t)l * 12 + h) * 4608];
    for (int u = t; u < 576; u += 256) {
      int kk = u / 3, c0 = (u % 3) * 8;
      uint4 val = *reinterpret_cast<const uint4*>(&vs[kk * 24 + c0]);
      const u16* pv = reinterpret_cast<const u16*>(&val);
#pragma unroll
      for (int i = 0; i < 8; ++i) Vt[(c0 + i) * 200 + kk] = pv[i];
    }
    for (int u = t; u < 1600; u += 256) Vt[4800 + u] = 0;
    __syncthreads();
    const bf16* Ps = &Ppv[((size_t)lc * 12 + h) * 36864 + (size_t)(bs * 64 + w * 16) * 192];
    f32x4 acc[2];
    acc[0] = (f32x4){0.f, 0.f, 0.f, 0.f};
    acc[1] = (f32x4){0.f, 0.f, 0.f, 0.f};
#pragma unroll
    for (int kt = 0; kt < 6; ++kt) {
      bf16x8 a = *reinterpret_cast<const bf16x8*>(&Ps[(size_t)c15 * 192 + kt * 32 + g * 8]);
      bf16x8 b0 = *reinterpret_cast<const bf16x8*>(Vt + (c15) * 200 + kt * 32 + g * 8);
      bf16x8 b1 = *reinterpret_cast<const bf16x8*>(Vt + (16 + c15) * 200 + kt * 32 + g * 8);
      acc[0] = __builtin_amdgcn_mfma_f32_16x16x32_bf16(a, b0, acc[0], 0, 0, 0);
      acc[1] = __builtin_amdgcn_mfma_f32_16x16x32_bf16(a, b1, acc[1], 0, 0, 0);
    }
#pragma unroll
    for (int nt = 0; nt < 2; ++nt)
#pragma unroll
      for (int i = 0; i < 4; ++i) {
        int c = nt * 16 + c15;
        if (c < 24) Ob[(w * 16 + 4 * g + i) * 26 + c] = acc[nt][i];
      }
    __syncthreads();
    if (t < 192) {
      int r = t / 3, c0 = (t % 3) * 8;
      int b = bs * 64 + r;
      size_t m = (size_t)b * 192 + l;
      uint4 gv4 = *reinterpret_cast<const uint4*>(&gbuf[m * 288 + h * 24 + c0]);
      const u16* gp = reinterpret_cast<const u16*>(&gv4);
      u16 opk[8];
#pragma unroll
      for (int i = 0; i < 8; ++i) {
        float gv = bf2f(gp[i]);
        float sg = 1.0f / (1.0f + __expf(-gv));
        opk[i] = f2bf(Ob[r * 26 + c0 + i] * sg);
      }
      *reinterpret_cast<uint4*>(&ogb[m * 288 + h * 24 + c0]) = *reinterpret_cast<uint4*>(opk);
    }
  }
}

// ---------------- kernel 5: out = ogb @ Wo + bo (MFMA, M-tile 64) ----------------
__global__ __launch_bounds__(256) void k_out(const bf16* __restrict__ ogb,
                                             const bf16* __restrict__ Wot,
                                             const float* __restrict__ bo,
                                             float* __restrict__ out) {
  int t = threadIdx.x;
  int w = t >> 6, lane = t & 63;
  int c15 = lane & 15, g = lane >> 4;
  int m0 = blockIdx.x * 64;
  int mrow = m0 + w * 16 + c15;
  f32x4 acc[8];
#pragma unroll
  for (int nt = 0; nt < 8; ++nt) acc[nt] = (f32x4){0.f, 0.f, 0.f, 0.f};
#pragma unroll
  for (int kt = 0; kt < 9; ++kt) {
    bf16x8 a = *reinterpret_cast<const bf16x8*>(&ogb[(size_t)mrow * 288 + kt * 32 + g * 8]);
    bf16x8 b[8];
#pragma unroll
    for (int nt = 0; nt < 8; ++nt)
      b[nt] = *reinterpret_cast<const bf16x8*>(&Wot[(size_t)(nt * 16 + c15) * 288 + kt * 32 + g * 8]);
#pragma unroll
    for (int nt = 0; nt < 8; ++nt)
      acc[nt] = __builtin_amdgcn_mfma_f32_16x16x32_bf16(a, b[nt], acc[nt], 0, 0, 0);
  }
#pragma unroll
  for (int nt = 0; nt < 8; ++nt) {
    int n = nt * 16 + c15;
    float bval = bo[n];
#pragma unroll
    for (int i = 0; i < 4; ++i) {
      int m = m0 + w * 16 + 4 * g + i;
      out[(size_t)m * 128 + n] = acc[nt][i] + bval;
    }
  }
}

extern "C" void kernel_launch(void* const* d_in, const int* in_sizes, int n_in,
                              void* d_out, int out_size, void* d_ws, size_t ws_size,
                              hipStream_t stream) {
  const float* z_in = (const float*)d_in[0];
  const float* ln_w = (const float*)d_in[1];
  const float* ln_b = (const float*)d_in[2];
  const float* Wq   = (const float*)d_in[3];
  const float* bq   = (const float*)d_in[4];
  const float* Wk   = (const float*)d_in[5];
  const float* bk   = (const float*)d_in[6];
  const float* Wv   = (const float*)d_in[7];
  const float* bv   = (const float*)d_in[8];
  const float* Wb   = (const float*)d_in[9];
  const float* bb   = (const float*)d_in[10];
  const float* Wg   = (const float*)d_in[11];
  const float* bg   = (const float*)d_in[12];
  const float* Wo   = (const float*)d_in[13];
  const float* bo   = (const float*)d_in[14];
  float* out = (float*)d_out;

  // workspace layout (bytes)
  char* ws = (char*)d_ws;
  bf16* q2    = (bf16*)(ws + 0);            // [192][12][192][24] (21,233,664)
  bf16* k2    = (bf16*)(ws + 21233664);     // [192][12][192][24]
  bf16* vb    = (bf16*)(ws + 42467328);     // [192][12][192][24]
  bf16* gbuf  = (bf16*)(ws + 63700992);     // [36864][288]
  bf16* ogb   = (bf16*)(ws + 84934656);     // [36864][288]
  bf16* zb    = (bf16*)(ws + 84934656);     // union: [36864][128], dead after k_proj
  bf16* Wcat  = (bf16*)(ws + 84934656 + 9437184);  // [1152][128], dead after k_proj
  float* biasb = (float*)(ws + 106168320);  // [12][192][192] f32 (1,769,472)
  bf16* Pb0   = (bf16*)(ws + 107937792);    // [16][12][192][192] (14,155,776)
  bf16* Wot   = (bf16*)(ws + 107937792);    // union with Pb0 (written after loop)
  bf16* Pb1   = (bf16*)(ws + 122093568);    // only used if ws allows
  bool big = ws_size >= 136249344ull;       // Pb1 fits -> double-buffered fused loop

  k_cvt<<<dim3(72), dim3(256), 0, stream>>>(Wq, Wk, Wv, Wg, Wcat);
  k_ln<<<dim3(9216), dim3(256), 0, stream>>>(z_in, ln_w, ln_b, Wb, bb, zb, biasb);
  k_proj<<<dim3(192, 12), dim3(256), 0, stream>>>(zb, Wcat, bq, bk, bv, bg,
                                                  q2, k2, vb, gbuf);
  if (big) {
    k_attpv<<<dim3(48, 12, 2), dim3(256), 0, stream>>>(
        q2, k2, biasb, vb, gbuf, Pb0, Pb0, ogb, 0, -1);
    for (int n = 1; n <= 12; ++n) {
      bf16* Pa = (n & 1) ? Pb1 : Pb0;
      bf16* Pp = ((n - 1) & 1) ? Pb1 : Pb0;
      k_attpv<<<dim3(48, 12, 2), dim3(256), 0, stream>>>(
          q2, k2, biasb, vb, gbuf, Pa, Pp, ogb, n < 12 ? n * 16 : -1, (n - 1) * 16);
    }
  } else {
    for (int n = 0; n < 12; ++n) {
      k_attpv<<<dim3(48, 12, 2), dim3(256), 0, stream>>>(
          q2, k2, biasb, vb, gbuf, Pb0, Pb0, ogb, n * 16, -1);
      k_attpv<<<dim3(48, 12, 2), dim3(256), 0, stream>>>(
          q2, k2, biasb, vb, gbuf, Pb0, Pb0, ogb, -1, n * 16);
    }
  }
  k_cvt2<<<dim3(18), dim3(256), 0, stream>>>(Wo, Wot);
  k_out<<<dim3(576), dim3(256), 0, stream>>>(ogb, Wot, bo, out);
}

// Round 6
// 283.764 us; speedup vs baseline: 2.4570x; 1.0507x over previous
//
#include <hip/hip_runtime.h>
#include <hip/hip_bf16.h>
#include <math.h>

typedef __hip_bfloat16 bf16;
typedef unsigned short u16;
typedef unsigned int u32;
typedef __attribute__((ext_vector_type(8))) short bf16x8;
typedef __attribute__((ext_vector_type(4))) float f32x4;

#define LL 36864  // L*L

__device__ __forceinline__ float wave_sum(float v) {
#pragma unroll
  for (int m = 32; m; m >>= 1) v += __shfl_xor(v, m, 64);
  return v;
}

__device__ __forceinline__ float bf2f(u16 u) {
  union { float f; u32 u; } c; c.u = ((u32)u) << 16; return c.f;
}
__device__ __forceinline__ u16 f2bf(float f) {  // RNE
  union { float f; u32 u; } c; c.f = f;
  u32 r = c.u + 0x7fffu + ((c.u >> 16) & 1u);
  return (u16)(r >> 16);
}

// ---------------- kernel 0a: Wq|Wk|Wv|Wg -> Wcat[jg][128] bf16 ----------------
__global__ __launch_bounds__(256) void k_cvt(const float* __restrict__ Wq,
                                             const float* __restrict__ Wk,
                                             const float* __restrict__ Wv,
                                             const float* __restrict__ Wg,
                                             bf16* __restrict__ Wcat) {
  int u = blockIdx.x * 256 + threadIdx.x;   // 18432 tasks
  if (u >= 18432) return;
  int jg = u >> 4, k0 = (u & 15) * 8;
  int sec = jg / 288, j = jg % 288;
  const float* W = sec == 0 ? Wq : sec == 1 ? Wk : sec == 2 ? Wv : Wg;
  u16 pk[8];
#pragma unroll
  for (int i = 0; i < 8; ++i) pk[i] = f2bf(W[(size_t)(k0 + i) * 288 + j]);
  *reinterpret_cast<uint4*>(&Wcat[(size_t)jg * 128 + k0]) = *reinterpret_cast<uint4*>(pk);
}

// ---------------- kernel 0b: Wo -> Wot[n][288] bf16 ----------------
__global__ __launch_bounds__(256) void k_cvt2(const float* __restrict__ Wo,
                                              bf16* __restrict__ Wot) {
  int u = blockIdx.x * 256 + threadIdx.x;   // 4608 tasks
  if (u >= 4608) return;
  int n = u / 36, k0 = (u % 36) * 8;
  u16 pk[8];
#pragma unroll
  for (int i = 0; i < 8; ++i) pk[i] = f2bf(Wo[(size_t)(k0 + i) * 128 + n]);
  *reinterpret_cast<uint4*>(&Wot[(size_t)n * 288 + k0]) = *reinterpret_cast<uint4*>(pk);
}

// ---------------- kernel 1: LayerNorm + fused bias projection ----------------
__global__ __launch_bounds__(256) void k_ln(const float* __restrict__ zin,
                                            const float* __restrict__ w_,
                                            const float* __restrict__ b_,
                                            const float* __restrict__ Wb,
                                            const float* __restrict__ bbv,
                                            bf16* __restrict__ zb,
                                            float* __restrict__ biasb) {
  int t = threadIdx.x;
  int wv = t >> 6, lane = t & 63;
  size_t m = (size_t)blockIdx.x * 4 + wv;
  const float2 v = *reinterpret_cast<const float2*>(&zin[m * 128 + lane * 2]);
  float s = wave_sum(v.x + v.y);
  float ss = wave_sum(v.x * v.x + v.y * v.y);
  float mean = s * (1.0f / 128.0f);
  float var = ss * (1.0f / 128.0f) - mean * mean;
  float rs = rsqrtf(var + 1e-5f);
  float o0 = (v.x - mean) * rs * w_[lane * 2] + b_[lane * 2];
  float o1 = (v.y - mean) * rs * w_[lane * 2 + 1] + b_[lane * 2 + 1];
  u32 pk = (u32)f2bf(o0) | ((u32)f2bf(o1) << 16);
  *reinterpret_cast<u32*>(&zb[m * 128 + lane * 2]) = pk;
  float accb[12];
#pragma unroll
  for (int h = 0; h < 12; ++h)
    accb[h] = o0 * Wb[(lane * 2) * 12 + h] + o1 * Wb[(lane * 2 + 1) * 12 + h];
#pragma unroll
  for (int h = 0; h < 12; ++h) accb[h] = wave_sum(accb[h]);
  if (lane == 0) {
    int kk = (int)m / 192, l = (int)m % 192;
#pragma unroll
    for (int h = 0; h < 12; ++h)
      biasb[(size_t)h * LL + (size_t)l * 192 + kk] = accb[h] + bbv[h];
  }
}

// ---------------- kernel 2: projections (MFMA, 192x96 tiles, 2-pass LDS bounce) ----
__global__ __launch_bounds__(256) void k_proj(const bf16* __restrict__ zb,
    const bf16* __restrict__ Wcat,
    const float* __restrict__ bq, const float* __restrict__ bk,
    const float* __restrict__ bv, const float* __restrict__ bg,
    bf16* __restrict__ q2, bf16* __restrict__ k2,
    bf16* __restrict__ vb, bf16* __restrict__ gbuf) {
  __shared__ __align__(16) u16 Sb[96 * 104];  // 19,968 B
  int t = threadIdx.x;
  int w = t >> 6, lane = t & 63;
  int c15 = lane & 15, g = lane >> 4;
  int wm = w & 1, wn = w >> 1;
  int bx = blockIdx.x, y = blockIdx.y;
  int sec = y / 3, h0 = (y % 3) * 4;
  int m0 = bx * 192;
  int jbase = y * 96;
  f32x4 acc[6][3];
#pragma unroll
  for (int mt = 0; mt < 6; ++mt)
#pragma unroll
    for (int nt = 0; nt < 3; ++nt) acc[mt][nt] = (f32x4){0.f, 0.f, 0.f, 0.f};
#pragma unroll
  for (int kt = 0; kt < 4; ++kt) {
    bf16x8 a[6], b[3];
#pragma unroll
    for (int mt = 0; mt < 6; ++mt)
      a[mt] = *reinterpret_cast<const bf16x8*>(
          &zb[(size_t)(m0 + wm * 96 + mt * 16 + c15) * 128 + kt * 32 + g * 8]);
#pragma unroll
    for (int nt = 0; nt < 3; ++nt)
      b[nt] = *reinterpret_cast<const bf16x8*>(
          &Wcat[(size_t)(jbase + wn * 48 + nt * 16 + c15) * 128 + kt * 32 + g * 8]);
#pragma unroll
    for (int mt = 0; mt < 6; ++mt)
#pragma unroll
      for (int nt = 0; nt < 3; ++nt)
        acc[mt][nt] = __builtin_amdgcn_mfma_f32_16x16x32_bf16(a[mt], b[nt], acc[mt][nt], 0, 0, 0);
  }
  const float* barr = sec == 0 ? bq : sec == 1 ? bk : sec == 2 ? bv : bg;
  for (int p = 0; p < 2; ++p) {
    if (p) __syncthreads();
    if (wm == p) {
#pragma unroll
      for (int nt = 0; nt < 3; ++nt) {
        int col = wn * 48 + nt * 16 + c15;
        float bval = barr[(y % 3) * 96 + col];
#pragma unroll
        for (int mt = 0; mt < 6; ++mt) {
          int rbase = mt * 16 + 4 * g;
#pragma unroll
          for (int i = 0; i < 4; ++i)
            Sb[(rbase + i) * 104 + col] = f2bf(acc[mt][nt][i] + bval);
        }
      }
    }
    __syncthreads();
    if (sec == 0) {
      bf16* dst0 = q2 + ((size_t)bx * 12 + h0) * 4608;
      for (int u = t; u < 1152; u += 256) {
        int hl = u / 288, v = u % 288;
        int off = (p * 288 + v) * 8;
        uint4 val = *reinterpret_cast<const uint4*>(
            &Sb[(v / 3) * 104 + hl * 24 + (v % 3) * 8]);
        *reinterpret_cast<uint4*>(&dst0[(size_t)hl * 4608 + off]) = val;
      }
    } else if (sec == 3) {
      for (int u = t; u < 1152; u += 256) {
        int mll = u / 12, col8 = (u % 12) * 8;
        uint4 val = *reinterpret_cast<const uint4*>(&Sb[mll * 104 + col8]);
        *reinterpret_cast<uint4*>(
            &gbuf[(size_t)(m0 + p * 96 + mll) * 288 + h0 * 24 + col8]) = val;
      }
    } else {
      bf16* dst = (sec == 1) ? k2 : vb;
      for (int u = t; u < 1152; u += 256) {
        int hl = u / 288, v = u % 288;
        int ml = p * 96 + v / 3, c0 = (v % 3) * 8;
        uint4 val = *reinterpret_cast<const uint4*>(
            &Sb[(v / 3) * 104 + hl * 24 + c0]);
        *reinterpret_cast<uint4*>(
            &dst[(((size_t)ml * 12 + h0 + hl) * 192 + bx) * 24 + c0]) = val;
      }
    }
  }
}

// ---------------- kernel 3: attention, role-switched ----------------
// att role: wave=(bq,h), loops l-tiles [ltb,lte) of chunk la0 -> P[lrel][h][b][kk]
// pv role:  block=(l-pair x, h): o = P @ V_l, sigmoid gate, -> ogb
__global__ __launch_bounds__(256) void k_attpv(const bf16* __restrict__ q2,
    const bf16* __restrict__ k2, const float* __restrict__ biasb,
    const bf16* __restrict__ vbuf, const bf16* __restrict__ gbuf,
    bf16* __restrict__ Patt, const bf16* __restrict__ Ppv,
    bf16* __restrict__ ogb, int la0, int lp0, int NT, int bqpb) {
  __shared__ __align__(16) char ldsraw[32256];
  int t = threadIdx.x;
  int w = t >> 6, lane = t & 63;
  int c15 = lane & 15, g = lane >> 4;
  const float sq_c = 0.20412414523193154f;  // 1/sqrt(24)
  bool is_att = (la0 >= 0) && (gridDim.z == 1 || blockIdx.z == 0);
  if (is_att) {
    int x = blockIdx.x, h = blockIdx.y;
    int bq, ltb, lte;
    if (bqpb == 4) { bq = x * 4 + w; ltb = 0; lte = NT; }
    else { bq = x * 2 + (w >> 1); int hf = w & 1; ltb = hf * (NT >> 1); lte = ltb + (NT >> 1); }
    u16* Sb = reinterpret_cast<u16*>(ldsraw) + (size_t)w * 3200;  // per-wave [16][200]
    const bf16* ks = &k2[((size_t)bq * 12 + h) * 4608];
    const float* bsrc = &biasb[(size_t)h * LL];
    for (int lt = ltb; lt < lte; ++lt) {
      int l0 = la0 + lt * 16;
      const bf16* qs = &q2[(((size_t)bq * 12 + h) * 192 + l0) * 24];
      bf16x8 afr = {0, 0, 0, 0, 0, 0, 0, 0};
      if (g < 3) afr = *reinterpret_cast<const bf16x8*>(&qs[c15 * 24 + g * 8]);
      f32x4 acc[12];
#pragma unroll
      for (int ct = 0; ct < 12; ++ct) {
        bf16x8 bfr = {0, 0, 0, 0, 0, 0, 0, 0};
        if (g < 3) bfr = *reinterpret_cast<const bf16x8*>(&ks[(ct * 16 + c15) * 24 + g * 8]);
        acc[ct] = __builtin_amdgcn_mfma_f32_16x16x32_bf16(afr, bfr, (f32x4){0.f, 0.f, 0.f, 0.f}, 0, 0, 0);
      }
#pragma unroll
      for (int i = 0; i < 4; ++i) {
        int l = l0 + 4 * g + i;
#pragma unroll
        for (int ct = 0; ct < 12; ++ct)
          acc[ct][i] = acc[ct][i] * sq_c + bsrc[(size_t)l * 192 + ct * 16 + c15];
      }
      float inv[4];
#pragma unroll
      for (int i = 0; i < 4; ++i) {
        float mx = -1e30f;
#pragma unroll
        for (int ct = 0; ct < 12; ++ct) mx = fmaxf(mx, acc[ct][i]);
#pragma unroll
        for (int msk = 1; msk < 16; msk <<= 1) mx = fmaxf(mx, __shfl_xor(mx, msk, 64));
        float sm = 0.f;
#pragma unroll
        for (int ct = 0; ct < 12; ++ct) {
          float e = __expf(acc[ct][i] - mx);
          acc[ct][i] = e;
          sm += e;
        }
#pragma unroll
        for (int msk = 1; msk < 16; msk <<= 1) sm += __shfl_xor(sm, msk, 64);
        inv[i] = 1.0f / sm;
      }
#pragma unroll
      for (int i = 0; i < 4; ++i)
#pragma unroll
        for (int ct = 0; ct < 12; ++ct)
          Sb[(4 * g + i) * 200 + ct * 16 + c15] = f2bf(acc[ct][i] * inv[i]);
      int lrel = l0 - la0;
      for (int u = lane; u < 384; u += 64) {
        int lloc = u / 24, oct = u % 24;
        uint4 val = *reinterpret_cast<const uint4*>(&Sb[lloc * 200 + oct * 8]);
        *reinterpret_cast<uint4*>(
            &Patt[(((size_t)(lrel + lloc) * 12 + h) * 192 + bq) * 192 + oct * 8]) = val;
      }
    }
  } else {
    if (lp0 < 0) return;
    int x = blockIdx.x, h = blockIdx.y;
    if (x >= NT * 8) return;
    u16* Vt = reinterpret_cast<u16*>(ldsraw);                        // 2 slabs [32][200]
    float* Ob = reinterpret_cast<float*>(ldsraw + 25600) + (size_t)w * 416;  // [16][26]
    for (int u = t; u < 1152; u += 256) {
      int s = u / 576, uu = u % 576;
      int kk = uu / 3, c0 = (uu % 3) * 8;
      int l = lp0 + x * 2 + s;
      uint4 val = *reinterpret_cast<const uint4*>(
          &vbuf[(((size_t)l * 12 + h) * 192 + kk) * 24 + c0]);
      const u16* pv = reinterpret_cast<const u16*>(&val);
#pragma unroll
      for (int i = 0; i < 8; ++i) Vt[s * 6400 + (c0 + i) * 200 + kk] = pv[i];
    }
    __syncthreads();
    int s = w >> 1, mh = w & 1;
    int l = lp0 + x * 2 + s;
    int lrel = x * 2 + s;
    const u16* Vw = Vt + s * 6400;
    bf16x8 bfr[6][2];
#pragma unroll
    for (int kt = 0; kt < 6; ++kt)
#pragma unroll
      for (int nt = 0; nt < 2; ++nt)
        bfr[kt][nt] = *reinterpret_cast<const bf16x8*>(
            &Vw[(nt * 16 + c15) * 200 + kt * 32 + g * 8]);
    const bf16* Ps = &Ppv[((size_t)lrel * 12 + h) * 36864];
#pragma unroll 2
    for (int mt = mh * 6; mt < mh * 6 + 6; ++mt) {
      f32x4 acc0 = (f32x4){0.f, 0.f, 0.f, 0.f};
      f32x4 acc1 = (f32x4){0.f, 0.f, 0.f, 0.f};
#pragma unroll
      for (int kt = 0; kt < 6; ++kt) {
        bf16x8 a = *reinterpret_cast<const bf16x8*>(
            &Ps[(size_t)(mt * 16 + c15) * 192 + kt * 32 + g * 8]);
        acc0 = __builtin_amdgcn_mfma_f32_16x16x32_bf16(a, bfr[kt][0], acc0, 0, 0, 0);
        acc1 = __builtin_amdgcn_mfma_f32_16x16x32_bf16(a, bfr[kt][1], acc1, 0, 0, 0);
      }
#pragma unroll
      for (int i = 0; i < 4; ++i) {
        Ob[(4 * g + i) * 26 + c15] = acc0[i];
        if (c15 < 8) Ob[(4 * g + i) * 26 + 16 + c15] = acc1[i];
      }
      if (lane < 48) {
        int r = lane / 3, c0 = (lane % 3) * 8;
        int b = mt * 16 + r;
        size_t m = (size_t)b * 192 + l;
        uint4 gv4 = *reinterpret_cast<const uint4*>(&gbuf[m * 288 + h * 24 + c0]);
        const u16* gp = reinterpret_cast<const u16*>(&gv4);
        u16 opk[8];
#pragma unroll
        for (int i = 0; i < 8; ++i) {
          float av = Ob[r * 26 + c0 + i];
          float sg = 1.0f / (1.0f + __expf(-bf2f(gp[i])));
          opk[i] = f2bf(av * sg);
        }
        *reinterpret_cast<uint4*>(&ogb[m * 288 + h * 24 + c0]) = *reinterpret_cast<uint4*>(opk);
      }
    }
  }
}

// ---------------- kernel 5: out = ogb @ Wo + bo (MFMA, M-tile 64) ----------------
__global__ __launch_bounds__(256) void k_out(const bf16* __restrict__ ogb,
                                             const bf16* __restrict__ Wot,
                                             const float* __restrict__ bo,
                                             float* __restrict__ out) {
  int t = threadIdx.x;
  int w = t >> 6, lane = t & 63;
  int c15 = lane & 15, g = lane >> 4;
  int m0 = blockIdx.x * 64;
  int mrow = m0 + w * 16 + c15;
  f32x4 acc[8];
#pragma unroll
  for (int nt = 0; nt < 8; ++nt) acc[nt] = (f32x4){0.f, 0.f, 0.f, 0.f};
#pragma unroll
  for (int kt = 0; kt < 9; ++kt) {
    bf16x8 a = *reinterpret_cast<const bf16x8*>(&ogb[(size_t)mrow * 288 + kt * 32 + g * 8]);
    bf16x8 b[8];
#pragma unroll
    for (int nt = 0; nt < 8; ++nt)
      b[nt] = *reinterpret_cast<const bf16x8*>(&Wot[(size_t)(nt * 16 + c15) * 288 + kt * 32 + g * 8]);
#pragma unroll
    for (int nt = 0; nt < 8; ++nt)
      acc[nt] = __builtin_amdgcn_mfma_f32_16x16x32_bf16(a, b[nt], acc[nt], 0, 0, 0);
  }
#pragma unroll
  for (int nt = 0; nt < 8; ++nt) {
    int n = nt * 16 + c15;
    float bval = bo[n];
#pragma unroll
    for (int i = 0; i < 4; ++i) {
      int m = m0 + w * 16 + 4 * g + i;
      out[(size_t)m * 128 + n] = acc[nt][i] + bval;
    }
  }
}

extern "C" void kernel_launch(void* const* d_in, const int* in_sizes, int n_in,
                              void* d_out, int out_size, void* d_ws, size_t ws_size,
                              hipStream_t stream) {
  const float* z_in = (const float*)d_in[0];
  const float* ln_w = (const float*)d_in[1];
  const float* ln_b = (const float*)d_in[2];
  const float* Wq   = (const float*)d_in[3];
  const float* bq   = (const float*)d_in[4];
  const float* Wk   = (const float*)d_in[5];
  const float* bk   = (const float*)d_in[6];
  const float* Wv   = (const float*)d_in[7];
  const float* bv   = (const float*)d_in[8];
  const float* Wb   = (const float*)d_in[9];
  const float* bb   = (const float*)d_in[10];
  const float* Wg   = (const float*)d_in[11];
  const float* bg   = (const float*)d_in[12];
  const float* Wo   = (const float*)d_in[13];
  const float* bo   = (const float*)d_in[14];
  float* out = (float*)d_out;

  char* ws = (char*)d_ws;
  bf16* q2    = (bf16*)(ws + 0);            // [b][h][l][24]
  bf16* k2    = (bf16*)(ws + 21233664);     // [b][h][kk][24]
  bf16* vb    = (bf16*)(ws + 42467328);     // [l][h][kk][24]
  bf16* gbuf  = (bf16*)(ws + 63700992);     // [m][288]
  bf16* ogb   = (bf16*)(ws + 84934656);     // [m][288]
  bf16* zb    = (bf16*)(ws + 84934656);     // union: dead after k_proj
  bf16* Wcat  = (bf16*)(ws + 94371840);     // union in ogb: dead after k_proj
  float* biasb = (float*)(ws + 106168320);  // [12][192][192] f32
  char* Pbase = ws + 107937792;
  bf16* Wot   = (bf16*)(ws + 107937792);    // union with P (written after pv loop)

  k_cvt<<<dim3(72), dim3(256), 0, stream>>>(Wq, Wk, Wv, Wg, Wcat);
  k_ln<<<dim3(9216), dim3(256), 0, stream>>>(z_in, ln_w, ln_b, Wb, bb, zb, biasb);
  k_proj<<<dim3(192, 12), dim3(256), 0, stream>>>(zb, Wcat, bq, bk, bv, bg,
                                                  q2, k2, vb, gbuf);
  const size_t PB = 107937792ull;
  if (ws_size >= PB + 169869312ull) {
    // full P, K read once, 2 big dispatches
    bf16* P = (bf16*)Pbase;
    k_attpv<<<dim3(96, 12, 1), dim3(256), 0, stream>>>(
        q2, k2, biasb, vb, gbuf, P, P, ogb, 0, -1, 12, 2);
    k_attpv<<<dim3(96, 12, 1), dim3(256), 0, stream>>>(
        q2, k2, biasb, vb, gbuf, P, P, ogb, -1, 0, 12, 2);
  } else if (ws_size >= PB + 2ull * 42467328ull) {
    // chunk 48, double-buffered fused
    bf16* P0 = (bf16*)Pbase;
    bf16* P1 = (bf16*)(Pbase + 42467328);
    for (int n = 0; n <= 4; ++n) {
      bf16* Pa = (n & 1) ? P1 : P0;
      bf16* Pp = ((n - 1) & 1) ? P1 : P0;
      int la = (n < 4) ? n * 48 : -1;
      int lp = (n >= 1) ? (n - 1) * 48 : -1;
      if (la >= 0)
        k_attpv<<<dim3(48, 12, 2), dim3(256), 0, stream>>>(
            q2, k2, biasb, vb, gbuf, Pa, Pp, ogb, la, lp, 3, 4);
      else
        k_attpv<<<dim3(24, 12, 1), dim3(256), 0, stream>>>(
            q2, k2, biasb, vb, gbuf, Pa, Pp, ogb, -1, lp, 3, 4);
    }
  } else if (ws_size >= PB + 2ull * 14155776ull) {
    // chunk 16, double-buffered fused
    bf16* P0 = (bf16*)Pbase;
    bf16* P1 = (bf16*)(Pbase + 14155776);
    for (int n = 0; n <= 12; ++n) {
      bf16* Pa = (n & 1) ? P1 : P0;
      bf16* Pp = ((n - 1) & 1) ? P1 : P0;
      int la = (n < 12) ? n * 16 : -1;
      int lp = (n >= 1) ? (n - 1) * 16 : -1;
      if (la >= 0)
        k_attpv<<<dim3(48, 12, 2), dim3(256), 0, stream>>>(
            q2, k2, biasb, vb, gbuf, Pa, Pp, ogb, la, lp, 1, 4);
      else
        k_attpv<<<dim3(8, 12, 1), dim3(256), 0, stream>>>(
            q2, k2, biasb, vb, gbuf, Pa, Pp, ogb, -1, lp, 1, 4);
    }
  } else {
    // chunk 16, single buffer, serial (proven 122,093,568-byte footprint)
    bf16* P0 = (bf16*)Pbase;
    for (int n = 0; n < 12; ++n) {
      k_attpv<<<dim3(48, 12, 1), dim3(256), 0, stream>>>(
          q2, k2, biasb, vb, gbuf, P0, P0, ogb, n * 16, -1, 1, 4);
      k_attpv<<<dim3(8, 12, 1), dim3(256), 0, stream>>>(
          q2, k2, biasb, vb, gbuf, P0, P0, ogb, -1, n * 16, 1, 4);
    }
  }
  k_cvt2<<<dim3(18), dim3(256), 0, stream>>>(Wo, Wot);
  k_out<<<dim3(576), dim3(256), 0, stream>>>(ogb, Wot, bo, out);
}

// Round 7
// 254.352 us; speedup vs baseline: 2.7411x; 1.1156x over previous
//
#include <hip/hip_runtime.h>
#include <hip/hip_bf16.h>
#include <math.h>

typedef __hip_bfloat16 bf16;
typedef unsigned short u16;
typedef unsigned int u32;
typedef __attribute__((ext_vector_type(8))) short bf16x8;
typedef __attribute__((ext_vector_type(4))) float f32x4;

#define LL 36864  // L*L

__device__ __forceinline__ float wave_sum(float v) {
#pragma unroll
  for (int m = 32; m; m >>= 1) v += __shfl_xor(v, m, 64);
  return v;
}

__device__ __forceinline__ float bf2f(u16 u) {
  union { float f; u32 u; } c; c.u = ((u32)u) << 16; return c.f;
}
__device__ __forceinline__ u16 f2bf(float f) {  // RNE
  union { float f; u32 u; } c; c.f = f;
  u32 r = c.u + 0x7fffu + ((c.u >> 16) & 1u);
  return (u16)(r >> 16);
}

// ---------------- kernel 0a: Wq|Wk|Wv|Wg -> Wcat[jg][128] bf16 ----------------
__global__ __launch_bounds__(256) void k_cvt(const float* __restrict__ Wq,
                                             const float* __restrict__ Wk,
                                             const float* __restrict__ Wv,
                                             const float* __restrict__ Wg,
                                             bf16* __restrict__ Wcat) {
  int u = blockIdx.x * 256 + threadIdx.x;   // 18432 tasks
  if (u >= 18432) return;
  int jg = u >> 4, k0 = (u & 15) * 8;
  int sec = jg / 288, j = jg % 288;
  const float* W = sec == 0 ? Wq : sec == 1 ? Wk : sec == 2 ? Wv : Wg;
  u16 pk[8];
#pragma unroll
  for (int i = 0; i < 8; ++i) pk[i] = f2bf(W[(size_t)(k0 + i) * 288 + j]);
  *reinterpret_cast<uint4*>(&Wcat[(size_t)jg * 128 + k0]) = *reinterpret_cast<uint4*>(pk);
}

// ---------------- kernel 0b: Wo -> Wot[n][288] bf16 ----------------
__global__ __launch_bounds__(256) void k_cvt2(const float* __restrict__ Wo,
                                              bf16* __restrict__ Wot) {
  int u = blockIdx.x * 256 + threadIdx.x;   // 4608 tasks
  if (u >= 4608) return;
  int n = u / 36, k0 = (u % 36) * 8;
  u16 pk[8];
#pragma unroll
  for (int i = 0; i < 8; ++i) pk[i] = f2bf(Wo[(size_t)(k0 + i) * 128 + n]);
  *reinterpret_cast<uint4*>(&Wot[(size_t)n * 288 + k0]) = *reinterpret_cast<uint4*>(pk);
}

// ---------------- kernel 1: LayerNorm + fused bias projection ----------------
__global__ __launch_bounds__(256) void k_ln(const float* __restrict__ zin,
                                            const float* __restrict__ w_,
                                            const float* __restrict__ b_,
                                            const float* __restrict__ Wb,
                                            const float* __restrict__ bbv,
                                            bf16* __restrict__ zb,
                                            float* __restrict__ biasb) {
  int t = threadIdx.x;
  int wv = t >> 6, lane = t & 63;
  size_t m = (size_t)blockIdx.x * 4 + wv;
  const float2 v = *reinterpret_cast<const float2*>(&zin[m * 128 + lane * 2]);
  float s = wave_sum(v.x + v.y);
  float ss = wave_sum(v.x * v.x + v.y * v.y);
  float mean = s * (1.0f / 128.0f);
  float var = ss * (1.0f / 128.0f) - mean * mean;
  float rs = rsqrtf(var + 1e-5f);
  float o0 = (v.x - mean) * rs * w_[lane * 2] + b_[lane * 2];
  float o1 = (v.y - mean) * rs * w_[lane * 2 + 1] + b_[lane * 2 + 1];
  u32 pk = (u32)f2bf(o0) | ((u32)f2bf(o1) << 16);
  *reinterpret_cast<u32*>(&zb[m * 128 + lane * 2]) = pk;
  float accb[12];
#pragma unroll
  for (int h = 0; h < 12; ++h)
    accb[h] = o0 * Wb[(lane * 2) * 12 + h] + o1 * Wb[(lane * 2 + 1) * 12 + h];
#pragma unroll
  for (int h = 0; h < 12; ++h) accb[h] = wave_sum(accb[h]);
  if (lane == 0) {
    int kk = (int)m / 192, l = (int)m % 192;
#pragma unroll
    for (int h = 0; h < 12; ++h)
      biasb[(size_t)h * LL + (size_t)l * 192 + kk] = accb[h] + bbv[h];
  }
}

// ---------------- kernel 2: projections (MFMA, 192x96 tiles, LDS-bounced stores) ----
// (round-4 proven version)
__global__ __launch_bounds__(256) void k_proj(const bf16* __restrict__ zb,
    const bf16* __restrict__ Wcat,
    const float* __restrict__ bq, const float* __restrict__ bk,
    const float* __restrict__ bv, const float* __restrict__ bg,
    bf16* __restrict__ q2, bf16* __restrict__ k2,
    bf16* __restrict__ vb, bf16* __restrict__ gbuf) {
  __shared__ __align__(16) u16 Sb[192 * 104];
  int t = threadIdx.x;
  int w = t >> 6, lane = t & 63;
  int c15 = lane & 15, g = lane >> 4;
  int wm = w & 1, wn = w >> 1;
  int bx = blockIdx.x, y = blockIdx.y;
  int sec = y / 3, h0 = (y % 3) * 4;
  int m0 = bx * 192;
  int jbase = y * 96;
  f32x4 acc[6][3];
#pragma unroll
  for (int mt = 0; mt < 6; ++mt)
#pragma unroll
    for (int nt = 0; nt < 3; ++nt) acc[mt][nt] = (f32x4){0.f, 0.f, 0.f, 0.f};
#pragma unroll
  for (int kt = 0; kt < 4; ++kt) {
    bf16x8 a[6], b[3];
#pragma unroll
    for (int mt = 0; mt < 6; ++mt)
      a[mt] = *reinterpret_cast<const bf16x8*>(
          &zb[(size_t)(m0 + wm * 96 + mt * 16 + c15) * 128 + kt * 32 + g * 8]);
#pragma unroll
    for (int nt = 0; nt < 3; ++nt)
      b[nt] = *reinterpret_cast<const bf16x8*>(
          &Wcat[(size_t)(jbase + wn * 48 + nt * 16 + c15) * 128 + kt * 32 + g * 8]);
#pragma unroll
    for (int mt = 0; mt < 6; ++mt)
#pragma unroll
      for (int nt = 0; nt < 3; ++nt)
        acc[mt][nt] = __builtin_amdgcn_mfma_f32_16x16x32_bf16(a[mt], b[nt], acc[mt][nt], 0, 0, 0);
  }
  const float* barr = sec == 0 ? bq : sec == 1 ? bk : sec == 2 ? bv : bg;
#pragma unroll
  for (int nt = 0; nt < 3; ++nt) {
    int col = wn * 48 + nt * 16 + c15;
    float bval = barr[(y % 3) * 96 + col];
#pragma unroll
    for (int mt = 0; mt < 6; ++mt) {
      int rbase = wm * 96 + mt * 16 + 4 * g;
#pragma unroll
      for (int i = 0; i < 4; ++i)
        Sb[(rbase + i) * 104 + col] = f2bf(acc[mt][nt][i] + bval);
    }
  }
  __syncthreads();
  if (sec == 0) {
    bf16* dst0 = q2 + ((size_t)bx * 12 + h0) * 4608;
    for (int u = t; u < 2304; u += 256) {
      int hl = u / 576, off = (u % 576) * 8;
      int ml = off / 24, c0 = off % 24;
      uint4 val = *reinterpret_cast<const uint4*>(&Sb[ml * 104 + hl * 24 + c0]);
      *reinterpret_cast<uint4*>(&dst0[(size_t)hl * 4608 + off]) = val;
    }
  } else if (sec == 3) {
    for (int u = t; u < 2304; u += 256) {
      int ml = u / 12, col = (u % 12) * 8;
      uint4 val = *reinterpret_cast<const uint4*>(&Sb[ml * 104 + col]);
      *reinterpret_cast<uint4*>(&gbuf[(size_t)(m0 + ml) * 288 + h0 * 24 + col]) = val;
    }
  } else {
    bf16* dst = (sec == 1) ? k2 : vb;
    for (int u = t; u < 2304; u += 256) {
      int hl = u / 576, off = (u % 576) * 8;
      int ml = off / 24, c0 = off % 24;
      uint4 val = *reinterpret_cast<const uint4*>(&Sb[ml * 104 + hl * 24 + c0]);
      *reinterpret_cast<uint4*>(
          &dst[(((size_t)ml * 12 + h0 + hl) * 192 + bx) * 24 + c0]) = val;
    }
  }
}

// ---------------- kernel 3: attention, role-switched ----------------
// att role (la0>=0, z==0): wave=(bq,h) via bq=x*4+w; loops NT l-tiles -> P[lrel][h][b][kk]
// pv role: block=(x -> l = lp0+x, h): 4 waves split 192 b-rows; o = P @ V_l, gate -> ogb
__global__ __launch_bounds__(256) void k_attpv(const bf16* __restrict__ q2,
    const bf16* __restrict__ k2, const float* __restrict__ biasb,
    const bf16* __restrict__ vbuf, const bf16* __restrict__ gbuf,
    bf16* __restrict__ Patt, const bf16* __restrict__ Ppv,
    bf16* __restrict__ ogb, int la0, int lp0, int NT, int NL) {
  __shared__ __align__(16) char ldsraw[25600];
  int t = threadIdx.x;
  int w = t >> 6, lane = t & 63;
  int c15 = lane & 15, g = lane >> 4;
  const float sq_c = 0.20412414523193154f;  // 1/sqrt(24)
  bool is_att = (la0 >= 0) && (gridDim.z == 1 || blockIdx.z == 0);
  if (is_att) {
    int x = blockIdx.x, h = blockIdx.y;
    int bq = x * 4 + w;
    u16* Sb = reinterpret_cast<u16*>(ldsraw) + (size_t)w * 3200;  // per-wave [16][200]
    const bf16* ks = &k2[((size_t)bq * 12 + h) * 4608];
    const float* bsrc = &biasb[(size_t)h * LL];
    for (int lt = 0; lt < NT; ++lt) {
      int l0 = la0 + lt * 16;
      const bf16* qs = &q2[(((size_t)bq * 12 + h) * 192 + l0) * 24];
      bf16x8 afr = {0, 0, 0, 0, 0, 0, 0, 0};
      if (g < 3) afr = *reinterpret_cast<const bf16x8*>(&qs[c15 * 24 + g * 8]);
      f32x4 acc[12];
#pragma unroll
      for (int ct = 0; ct < 12; ++ct) {
        bf16x8 bfr = {0, 0, 0, 0, 0, 0, 0, 0};
        if (g < 3) bfr = *reinterpret_cast<const bf16x8*>(&ks[(ct * 16 + c15) * 24 + g * 8]);
        acc[ct] = __builtin_amdgcn_mfma_f32_16x16x32_bf16(afr, bfr, (f32x4){0.f, 0.f, 0.f, 0.f}, 0, 0, 0);
      }
#pragma unroll
      for (int i = 0; i < 4; ++i) {
        int l = l0 + 4 * g + i;
#pragma unroll
        for (int ct = 0; ct < 12; ++ct)
          acc[ct][i] = acc[ct][i] * sq_c + bsrc[(size_t)l * 192 + ct * 16 + c15];
      }
      float inv[4];
#pragma unroll
      for (int i = 0; i < 4; ++i) {
        float mx = -1e30f;
#pragma unroll
        for (int ct = 0; ct < 12; ++ct) mx = fmaxf(mx, acc[ct][i]);
#pragma unroll
        for (int msk = 1; msk < 16; msk <<= 1) mx = fmaxf(mx, __shfl_xor(mx, msk, 64));
        float sm = 0.f;
#pragma unroll
        for (int ct = 0; ct < 12; ++ct) {
          float e = __expf(acc[ct][i] - mx);
          acc[ct][i] = e;
          sm += e;
        }
#pragma unroll
        for (int msk = 1; msk < 16; msk <<= 1) sm += __shfl_xor(sm, msk, 64);
        inv[i] = 1.0f / sm;
      }
#pragma unroll
      for (int i = 0; i < 4; ++i)
#pragma unroll
        for (int ct = 0; ct < 12; ++ct)
          Sb[(4 * g + i) * 200 + ct * 16 + c15] = f2bf(acc[ct][i] * inv[i]);
      int lrel = l0 - la0;
      for (int u = lane; u < 384; u += 64) {
        int lloc = u / 24, oct = u % 24;
        uint4 val = *reinterpret_cast<const uint4*>(&Sb[lloc * 200 + oct * 8]);
        *reinterpret_cast<uint4*>(
            &Patt[(((size_t)(lrel + lloc) * 12 + h) * 192 + bq) * 192 + oct * 8]) = val;
      }
    }
  } else {
    if (lp0 < 0) return;
    int x = blockIdx.x, h = blockIdx.y;
    if (x >= NL) return;
    u16* Vt = reinterpret_cast<u16*>(ldsraw);                              // [32][200]
    float* Ob = reinterpret_cast<float*>(ldsraw + 12800) + (size_t)w * 416; // [16][26]
    int l = lp0 + x;
    int lrel = x;
    const bf16* vs = &vbuf[((size_t)l * 12 + h) * 4608];
    for (int u = t; u < 576; u += 256) {
      int kk = u / 3, c0 = (u % 3) * 8;
      uint4 val = *reinterpret_cast<const uint4*>(&vs[kk * 24 + c0]);
      const u16* pv = reinterpret_cast<const u16*>(&val);
#pragma unroll
      for (int i = 0; i < 8; ++i) Vt[(c0 + i) * 200 + kk] = pv[i];
    }
    __syncthreads();
    bf16x8 bfr[6][2];
#pragma unroll
    for (int kt = 0; kt < 6; ++kt)
#pragma unroll
      for (int nt = 0; nt < 2; ++nt)
        bfr[kt][nt] = *reinterpret_cast<const bf16x8*>(
            &Vt[(nt * 16 + c15) * 200 + kt * 32 + g * 8]);
    const bf16* Ps = &Ppv[((size_t)lrel * 12 + h) * 36864];
#pragma unroll
    for (int mi = 0; mi < 3; ++mi) {
      int mt = w * 3 + mi;
      f32x4 acc0 = (f32x4){0.f, 0.f, 0.f, 0.f};
      f32x4 acc1 = (f32x4){0.f, 0.f, 0.f, 0.f};
#pragma unroll
      for (int kt = 0; kt < 6; ++kt) {
        bf16x8 a = *reinterpret_cast<const bf16x8*>(
            &Ps[(size_t)(mt * 16 + c15) * 192 + kt * 32 + g * 8]);
        acc0 = __builtin_amdgcn_mfma_f32_16x16x32_bf16(a, bfr[kt][0], acc0, 0, 0, 0);
        acc1 = __builtin_amdgcn_mfma_f32_16x16x32_bf16(a, bfr[kt][1], acc1, 0, 0, 0);
      }
#pragma unroll
      for (int i = 0; i < 4; ++i) {
        Ob[(4 * g + i) * 26 + c15] = acc0[i];
        if (c15 < 8) Ob[(4 * g + i) * 26 + 16 + c15] = acc1[i];
      }
      if (lane < 48) {
        int r = lane / 3, c0 = (lane % 3) * 8;
        int b = mt * 16 + r;
        size_t m = (size_t)b * 192 + l;
        uint4 gv4 = *reinterpret_cast<const uint4*>(&gbuf[m * 288 + h * 24 + c0]);
        const u16* gp = reinterpret_cast<const u16*>(&gv4);
        u16 opk[8];
#pragma unroll
        for (int i = 0; i < 8; ++i) {
          float av = Ob[r * 26 + c0 + i];
          float sg = 1.0f / (1.0f + __expf(-bf2f(gp[i])));
          opk[i] = f2bf(av * sg);
        }
        *reinterpret_cast<uint4*>(&ogb[m * 288 + h * 24 + c0]) = *reinterpret_cast<uint4*>(opk);
      }
    }
  }
}

// ---------------- kernel 5: out = ogb @ Wo + bo (MFMA, M-tile 64) ----------------
__global__ __launch_bounds__(256) void k_out(const bf16* __restrict__ ogb,
                                             const bf16* __restrict__ Wot,
                                             const float* __restrict__ bo,
                                             float* __restrict__ out) {
  int t = threadIdx.x;
  int w = t >> 6, lane = t & 63;
  int c15 = lane & 15, g = lane >> 4;
  int m0 = blockIdx.x * 64;
  int mrow = m0 + w * 16 + c15;
  f32x4 acc[8];
#pragma unroll
  for (int nt = 0; nt < 8; ++nt) acc[nt] = (f32x4){0.f, 0.f, 0.f, 0.f};
#pragma unroll
  for (int kt = 0; kt < 9; ++kt) {
    bf16x8 a = *reinterpret_cast<const bf16x8*>(&ogb[(size_t)mrow * 288 + kt * 32 + g * 8]);
    bf16x8 b[8];
#pragma unroll
    for (int nt = 0; nt < 8; ++nt)
      b[nt] = *reinterpret_cast<const bf16x8*>(&Wot[(size_t)(nt * 16 + c15) * 288 + kt * 32 + g * 8]);
#pragma unroll
    for (int nt = 0; nt < 8; ++nt)
      acc[nt] = __builtin_amdgcn_mfma_f32_16x16x32_bf16(a, b[nt], acc[nt], 0, 0, 0);
  }
#pragma unroll
  for (int nt = 0; nt < 8; ++nt) {
    int n = nt * 16 + c15;
    float bval = bo[n];
#pragma unroll
    for (int i = 0; i < 4; ++i) {
      int m = m0 + w * 16 + 4 * g + i;
      out[(size_t)m * 128 + n] = acc[nt][i] + bval;
    }
  }
}

extern "C" void kernel_launch(void* const* d_in, const int* in_sizes, int n_in,
                              void* d_out, int out_size, void* d_ws, size_t ws_size,
                              hipStream_t stream) {
  const float* z_in = (const float*)d_in[0];
  const float* ln_w = (const float*)d_in[1];
  const float* ln_b = (const float*)d_in[2];
  const float* Wq   = (const float*)d_in[3];
  const float* bq   = (const float*)d_in[4];
  const float* Wk   = (const float*)d_in[5];
  const float* bk   = (const float*)d_in[6];
  const float* Wv   = (const float*)d_in[7];
  const float* bv   = (const float*)d_in[8];
  const float* Wb   = (const float*)d_in[9];
  const float* bb   = (const float*)d_in[10];
  const float* Wg   = (const float*)d_in[11];
  const float* bg   = (const float*)d_in[12];
  const float* Wo   = (const float*)d_in[13];
  const float* bo   = (const float*)d_in[14];
  float* out = (float*)d_out;

  char* ws = (char*)d_ws;
  bf16* q2    = (bf16*)(ws + 0);            // [b][h][l][24]
  bf16* k2    = (bf16*)(ws + 21233664);     // [b][h][kk][24]
  bf16* vb    = (bf16*)(ws + 42467328);     // [l][h][kk][24]
  bf16* gbuf  = (bf16*)(ws + 63700992);     // [m][288]
  bf16* ogb   = (bf16*)(ws + 84934656);     // [m][288]
  bf16* zb    = (bf16*)(ws + 84934656);     // union: dead after k_proj
  bf16* Wcat  = (bf16*)(ws + 94371840);     // union in ogb: dead after k_proj
  float* biasb = (float*)(ws + 106168320);  // [12][192][192] f32
  char* Pbase = ws + 107937792;
  bf16* Wot   = (bf16*)(ws + 107937792);    // union with P (written after pv loop)

  k_cvt<<<dim3(72), dim3(256), 0, stream>>>(Wq, Wk, Wv, Wg, Wcat);
  k_ln<<<dim3(9216), dim3(256), 0, stream>>>(z_in, ln_w, ln_b, Wb, bb, zb, biasb);
  k_proj<<<dim3(192, 12), dim3(256), 0, stream>>>(zb, Wcat, bq, bk, bv, bg,
                                                  q2, k2, vb, gbuf);
  const size_t PB = 107937792ull;
  // choose chunk size CL (in l-rows) by available workspace
  int CL;
  if      (ws_size >= PB + 169869312ull) CL = 192;  // full P, single buffer
  else if (ws_size >= PB + 84934656ull)  CL = 48;   // dbuf 48
  else if (ws_size >= PB + 56623104ull)  CL = 32;   // dbuf 32
  else if (ws_size >= PB + 28311552ull)  CL = 16;   // dbuf 16
  else                                   CL = -16;  // serial 16, single buffer
  if (CL == 192) {
    bf16* P = (bf16*)Pbase;
    k_attpv<<<dim3(48, 12, 1), dim3(256), 0, stream>>>(
        q2, k2, biasb, vb, gbuf, P, P, ogb, 0, -1, 12, 192);
    k_attpv<<<dim3(192, 12, 1), dim3(256), 0, stream>>>(
        q2, k2, biasb, vb, gbuf, P, P, ogb, -1, 0, 12, 192);
  } else if (CL > 0) {
    int nch = 192 / CL;
    size_t csz = (size_t)CL * 884736ull;  // CL*12*192*192*2 bytes
    bf16* P0 = (bf16*)Pbase;
    bf16* P1 = (bf16*)(Pbase + csz);
    int NT = CL / 16;
    for (int n = 0; n <= nch; ++n) {
      bf16* Pa = (n & 1) ? P1 : P0;
      bf16* Pp = ((n - 1) & 1) ? P1 : P0;
      int la = (n < nch) ? n * CL : -1;
      int lp = (n >= 1) ? (n - 1) * CL : -1;
      if (la >= 0 && lp >= 0)
        k_attpv<<<dim3(48 > CL ? 48 : CL, 12, 2), dim3(256), 0, stream>>>(
            q2, k2, biasb, vb, gbuf, Pa, Pp, ogb, la, lp, NT, CL);
      else if (la >= 0)
        k_attpv<<<dim3(48, 12, 1), dim3(256), 0, stream>>>(
            q2, k2, biasb, vb, gbuf, Pa, Pp, ogb, la, -1, NT, CL);
      else
        k_attpv<<<dim3(CL, 12, 1), dim3(256), 0, stream>>>(
            q2, k2, biasb, vb, gbuf, Pa, Pp, ogb, -1, lp, NT, CL);
    }
  } else {
    bf16* P0 = (bf16*)Pbase;
    for (int n = 0; n < 12; ++n) {
      k_attpv<<<dim3(48, 12, 1), dim3(256), 0, stream>>>(
          q2, k2, biasb, vb, gbuf, P0, P0, ogb, n * 16, -1, 1, 16);
      k_attpv<<<dim3(16, 12, 1), dim3(256), 0, stream>>>(
          q2, k2, biasb, vb, gbuf, P0, P0, ogb, -1, n * 16, 1, 16);
    }
  }
  k_cvt2<<<dim3(18), dim3(256), 0, stream>>>(Wo, Wot);
  k_out<<<dim3(576), dim3(256), 0, stream>>>(ogb, Wot, bo, out);
}